// Round 1
// baseline (17855.046 us; speedup 1.0000x reference)
//
#include <hip/hip_runtime.h>
#include <hip/hip_bf16.h>

#define SLOW 32
#define MSG 16
#define TSTEPS 4
#define BATCH 8
#define NI0 256
#define NO0 128
#define NI1 128
#define NO1 64

__device__ __forceinline__ float sigf(float x) { return 1.f / (1.f + __expf(-x)); }
__device__ __forceinline__ float tanh_apx(float x) {
    float xc = fminf(fmaxf(x, -15.f), 15.f);
    float e = __expf(-2.f * xc);
    return (1.f - e) / (1.f + e);
}

// ---------------------------------------------------------------------------
// merge: for slow channels s<16, replace h/c with mean over batch (in place)
// layout of state: [s][b][no][ni]   (plane = NO*NI per (s,b))
// ---------------------------------------------------------------------------
__global__ void k_merge(float* __restrict__ h0, float* __restrict__ c0,
                        float* __restrict__ h1, float* __restrict__ c1) {
    int idx = blockIdx.x * blockDim.x + threadIdx.x;
    const int P0 = NO0 * NI0;          // 32768
    const int P1 = NO1 * NI1;          // 8192
    const int N0 = 16 * P0;            // 524288
    const int N1 = 16 * P1;            // 131072
    float* h; float* c; int s, p, plane;
    if (idx < N0) { h = h0; c = c0; s = idx / P0; p = idx % P0; plane = P0; }
    else {
        idx -= N0;
        if (idx >= N1) return;
        h = h1; c = c1; s = idx / P1; p = idx % P1; plane = P1;
    }
    size_t base = (size_t)(s * BATCH) * plane + p;
    float sh = 0.f, sc = 0.f;
#pragma unroll
    for (int b = 0; b < BATCH; b++) { sh += h[base + (size_t)b * plane]; sc += c[base + (size_t)b * plane]; }
    sh *= 0.125f; sc *= 0.125f;
#pragma unroll
    for (int b = 0; b < BATCH; b++) { h[base + (size_t)b * plane] = sh; c[base + (size_t)b * plane] = sc; }
}

// ---------------------------------------------------------------------------
// Layer 0: block = (b, no) [8*128 blocks], threads = ni (256)
// f-message: only channel 0 nonzero = inp[t,b,ni]  -> per-thread mi*Wi[0,k]
// b-message: nb1[b,no,:] (prev step layer-1 nb)     -> block-shared g-base
// outputs: updated h0,c0; xf1T[b][k][no] = sum_m nf[b,no,m]*Wi[m,k]
// (layer-0 bm/nb is unused by the reference -> skipped)
// ---------------------------------------------------------------------------
#define MICRO_ITER_L0(HI, HO)                                                  \
    do {                                                                       \
        _Pragma("unroll")                                                      \
        for (int s = 0; s < SLOW; s++) {                                       \
            float a0 = gsh[s]            + mi * wi0[s];                        \
            float a1 = gsh[SLOW + s]     + mi * wi0[SLOW + s];                 \
            float a2 = gsh[2 * SLOW + s] + mi * wi0[2 * SLOW + s];             \
            float a3 = gsh[3 * SLOW + s] + mi * wi0[3 * SLOW + s];             \
            _Pragma("unroll")                                                  \
            for (int j = 0; j < SLOW; j += 4) {                                \
                float4 w0 = *(const float4*)&WhT[(s) * SLOW + j];              \
                float4 w1 = *(const float4*)&WhT[(SLOW + s) * SLOW + j];       \
                float4 w2 = *(const float4*)&WhT[(2 * SLOW + s) * SLOW + j];   \
                float4 w3 = *(const float4*)&WhT[(3 * SLOW + s) * SLOW + j];   \
                float x0 = HI[j], x1 = HI[j + 1], x2 = HI[j + 2], x3 = HI[j + 3]; \
                a0 += x0 * w0.x + x1 * w0.y + x2 * w0.z + x3 * w0.w;           \
                a1 += x0 * w1.x + x1 * w1.y + x2 * w1.z + x3 * w1.w;           \
                a2 += x0 * w2.x + x1 * w2.y + x2 * w2.z + x3 * w2.w;           \
                a3 += x0 * w3.x + x1 * w3.y + x2 * w3.z + x3 * w3.w;           \
            }                                                                  \
            float cg = tanh_apx(a2);                                           \
            float cn = sigf(a1) * c[s] + sigf(a0) * cg;                        \
            c[s] = cn;                                                         \
            HO[s] = sigf(a3) * tanh_apx(cn);                                   \
        }                                                                      \
    } while (0)

__global__ __launch_bounds__(256) void k_l0(
    const float* __restrict__ inp, const float* __restrict__ Wi,
    const float* __restrict__ Wh, const float* __restrict__ b_lstm,
    const float* __restrict__ Wf, const float* __restrict__ bf,
    const float* __restrict__ ln_fs, const float* __restrict__ ln_fb,
    float* __restrict__ h0g, float* __restrict__ c0g,
    const float* __restrict__ nb1, float* __restrict__ xf1T, int t) {
    int b = blockIdx.x >> 7;
    int no = blockIdx.x & 127;
    int ni = threadIdx.x;

    __shared__ __align__(16) float WhT[128 * SLOW];
    __shared__ __align__(16) float WfT[MSG * SLOW];
    __shared__ float gsh[128];
    __shared__ float wi0[128];
    __shared__ float red[4][MSG];
    __shared__ float nfsh[MSG];
    __shared__ float lnf[2 * MSG];
    __shared__ float bfs[MSG];

    for (int idx = threadIdx.x; idx < 128 * SLOW; idx += 256)
        WhT[idx] = Wh[(idx & 31) * 128 + (idx >> 5)];
    for (int idx = threadIdx.x; idx < MSG * SLOW; idx += 256)
        WfT[idx] = Wf[(idx & 31) * MSG + (idx >> 5)];
    if (threadIdx.x < 128) {
        int k = threadIdx.x;
        float acc = b_lstm[k];
        const float* nbr = nb1 + ((size_t)b * NO0 + no) * MSG;
#pragma unroll
        for (int m = 0; m < MSG; m++) acc += nbr[m] * Wi[(MSG + m) * 128 + k];
        gsh[k] = acc;
        wi0[k] = Wi[k];
    }
    if (threadIdx.x < MSG) {
        lnf[threadIdx.x] = ln_fs[threadIdx.x];
        lnf[MSG + threadIdx.x] = ln_fb[threadIdx.x];
        bfs[threadIdx.x] = bf[threadIdx.x];
    }

    float mi = inp[((size_t)t * BATCH + b) * NI0 + ni];
    const size_t SS = (size_t)BATCH * NO0 * NI0;
    size_t base = ((size_t)b * NO0 + no) * NI0 + ni;

    float h[SLOW], hn[SLOW], c[SLOW];
#pragma unroll
    for (int s = 0; s < SLOW; s++) { h[s] = h0g[s * SS + base]; c[s] = c0g[s * SS + base]; }
    __syncthreads();

    MICRO_ITER_L0(h, hn);
    MICRO_ITER_L0(hn, h);

    // fm = LN(h @ Wf + bf)
    float fm[MSG];
#pragma unroll
    for (int m = 0; m < MSG; m++) {
        float a = bfs[m];
#pragma unroll
        for (int j = 0; j < SLOW; j += 4) {
            float4 w = *(const float4*)&WfT[m * SLOW + j];
            a += h[j] * w.x + h[j + 1] * w.y + h[j + 2] * w.z + h[j + 3] * w.w;
        }
        fm[m] = a;
    }
    float mean = 0.f;
#pragma unroll
    for (int m = 0; m < MSG; m++) mean += fm[m];
    mean *= (1.f / MSG);
    float var = 0.f;
#pragma unroll
    for (int m = 0; m < MSG; m++) { float d = fm[m] - mean; var += d * d; }
    var *= (1.f / MSG);
    float rs = rsqrtf(var + 1e-6f);
#pragma unroll
    for (int m = 0; m < MSG; m++) fm[m] = (fm[m] - mean) * rs * lnf[m] + lnf[MSG + m];

    // write back state
#pragma unroll
    for (int s = 0; s < SLOW; s++) { h0g[s * SS + base] = h[s]; c0g[s * SS + base] = c[s]; }

    // reduce fm over ni (256 threads) -> nf[b,no,:]
    int lane = threadIdx.x & 63, wv = threadIdx.x >> 6;
#pragma unroll
    for (int m = 0; m < MSG; m++) {
        float v = fm[m];
#pragma unroll
        for (int d = 1; d < 64; d <<= 1) v += __shfl_xor(v, d);
        if (lane == 0) red[wv][m] = v;
    }
    __syncthreads();
    if (threadIdx.x < MSG) {
        int m = threadIdx.x;
        nfsh[m] = (red[0][m] + red[1][m] + red[2][m] + red[3][m]) * (1.f / NI0);
    }
    __syncthreads();
    // xf1T[b][k][no] = sum_m nf[m] * Wi[m,k]
    if (threadIdx.x < 128) {
        int k = threadIdx.x;
        float a = 0.f;
#pragma unroll
        for (int m = 0; m < MSG; m++) a += nfsh[m] * Wi[m * 128 + k];
        xf1T[((size_t)b * 128 + k) * NO0 + no] = a;
    }
}

// ---------------------------------------------------------------------------
// Layer 1: block = (b, no) [8*64 blocks], threads = ni (128)
// f-message: xf1T[b][k][ni] (precomputed by k_l0)
// b-message: grad/oh scalars (prev step error) -> block-shared g-base
// outputs: h1,c1; bm_g (per-cell LN'd bm, for nb reduce); outsum[b,no]
// ---------------------------------------------------------------------------
#define MICRO_ITER_L1(HI, HO)                                                  \
    do {                                                                       \
        _Pragma("unroll")                                                      \
        for (int s = 0; s < SLOW; s++) {                                       \
            float a0 = gsh[s]            + xfb[(size_t)(s) * NI1 + ni];        \
            float a1 = gsh[SLOW + s]     + xfb[(size_t)(SLOW + s) * NI1 + ni]; \
            float a2 = gsh[2 * SLOW + s] + xfb[(size_t)(2 * SLOW + s) * NI1 + ni]; \
            float a3 = gsh[3 * SLOW + s] + xfb[(size_t)(3 * SLOW + s) * NI1 + ni]; \
            _Pragma("unroll")                                                  \
            for (int j = 0; j < SLOW; j += 4) {                                \
                float4 w0 = *(const float4*)&WhT[(s) * SLOW + j];              \
                float4 w1 = *(const float4*)&WhT[(SLOW + s) * SLOW + j];       \
                float4 w2 = *(const float4*)&WhT[(2 * SLOW + s) * SLOW + j];   \
                float4 w3 = *(const float4*)&WhT[(3 * SLOW + s) * SLOW + j];   \
                float x0 = HI[j], x1 = HI[j + 1], x2 = HI[j + 2], x3 = HI[j + 3]; \
                a0 += x0 * w0.x + x1 * w0.y + x2 * w0.z + x3 * w0.w;           \
                a1 += x0 * w1.x + x1 * w1.y + x2 * w1.z + x3 * w1.w;           \
                a2 += x0 * w2.x + x1 * w2.y + x2 * w2.z + x3 * w2.w;           \
                a3 += x0 * w3.x + x1 * w3.y + x2 * w3.z + x3 * w3.w;           \
            }                                                                  \
            float cg = tanh_apx(a2);                                           \
            float cn = sigf(a1) * c[s] + sigf(a0) * cg;                        \
            c[s] = cn;                                                         \
            HO[s] = sigf(a3) * tanh_apx(cn);                                   \
        }                                                                      \
    } while (0)

__global__ __launch_bounds__(128) void k_l1(
    const float* __restrict__ Wi, const float* __restrict__ Wh,
    const float* __restrict__ b_lstm,
    const float* __restrict__ Wf, const float* __restrict__ bf,
    const float* __restrict__ ln_fs, const float* __restrict__ ln_fb,
    const float* __restrict__ Wb, const float* __restrict__ bwb,
    const float* __restrict__ ln_bs, const float* __restrict__ ln_bb,
    float* __restrict__ h1g, float* __restrict__ c1g,
    const float* __restrict__ xf1T, const float* __restrict__ gradP,
    const float* __restrict__ ohP,
    float* __restrict__ bm_g, float* __restrict__ outsum) {
    int b = blockIdx.x >> 6;
    int no = blockIdx.x & 63;
    int ni = threadIdx.x;

    __shared__ __align__(16) float WhT[128 * SLOW];
    __shared__ __align__(16) float WfT[MSG * SLOW];
    __shared__ __align__(16) float WbT[MSG * SLOW];
    __shared__ float gsh[128];
    __shared__ float lnf[2 * MSG], lnb[2 * MSG], bfs[MSG], bbs[MSG];
    __shared__ float red[2];

    for (int idx = threadIdx.x; idx < 128 * SLOW; idx += 128)
        WhT[idx] = Wh[(idx & 31) * 128 + (idx >> 5)];
    for (int idx = threadIdx.x; idx < MSG * SLOW; idx += 128) {
        WfT[idx] = Wf[(idx & 31) * MSG + (idx >> 5)];
        WbT[idx] = Wb[(idx & 31) * MSG + (idx >> 5)];
    }
    {
        int k = threadIdx.x;  // 128 threads exactly
        float g = gradP[b * NO1 + no], oh = ohP[b * NO1 + no];
        gsh[k] = b_lstm[k] + g * Wi[MSG * 128 + k] + oh * Wi[(MSG + 1) * 128 + k];
    }
    if (threadIdx.x < MSG) {
        int m = threadIdx.x;
        lnf[m] = ln_fs[m]; lnf[MSG + m] = ln_fb[m];
        lnb[m] = ln_bs[m]; lnb[MSG + m] = ln_bb[m];
        bfs[m] = bf[m]; bbs[m] = bwb[m];
    }

    const float* xfb = xf1T + (size_t)b * 128 * NI1;  // [k][ni]
    const size_t SS = (size_t)BATCH * NO1 * NI1;
    size_t base = ((size_t)b * NO1 + no) * NI1 + ni;

    float h[SLOW], hn[SLOW], c[SLOW];
#pragma unroll
    for (int s = 0; s < SLOW; s++) { h[s] = h1g[s * SS + base]; c[s] = c1g[s * SS + base]; }
    __syncthreads();

    MICRO_ITER_L1(h, hn);
    MICRO_ITER_L1(hn, h);

    // fm = LN(h@Wf+bf) -> need channel 0 after LN (full LN required)
    float fm[MSG];
#pragma unroll
    for (int m = 0; m < MSG; m++) {
        float a = bfs[m];
#pragma unroll
        for (int j = 0; j < SLOW; j += 4) {
            float4 w = *(const float4*)&WfT[m * SLOW + j];
            a += h[j] * w.x + h[j + 1] * w.y + h[j + 2] * w.z + h[j + 3] * w.w;
        }
        fm[m] = a;
    }
    {
        float mean = 0.f;
#pragma unroll
        for (int m = 0; m < MSG; m++) mean += fm[m];
        mean *= (1.f / MSG);
        float var = 0.f;
#pragma unroll
        for (int m = 0; m < MSG; m++) { float d = fm[m] - mean; var += d * d; }
        var *= (1.f / MSG);
        float rs = rsqrtf(var + 1e-6f);
#pragma unroll
        for (int m = 0; m < MSG; m++) fm[m] = (fm[m] - mean) * rs * lnf[m] + lnf[MSG + m];
    }
    // bm = LN(h@Wb+bwb)
    float bm[MSG];
#pragma unroll
    for (int m = 0; m < MSG; m++) {
        float a = bbs[m];
#pragma unroll
        for (int j = 0; j < SLOW; j += 4) {
            float4 w = *(const float4*)&WbT[m * SLOW + j];
            a += h[j] * w.x + h[j + 1] * w.y + h[j + 2] * w.z + h[j + 3] * w.w;
        }
        bm[m] = a;
    }
    {
        float mean = 0.f;
#pragma unroll
        for (int m = 0; m < MSG; m++) mean += bm[m];
        mean *= (1.f / MSG);
        float var = 0.f;
#pragma unroll
        for (int m = 0; m < MSG; m++) { float d = bm[m] - mean; var += d * d; }
        var *= (1.f / MSG);
        float rs = rsqrtf(var + 1e-6f);
#pragma unroll
        for (int m = 0; m < MSG; m++) bm[m] = (bm[m] - mean) * rs * lnb[m] + lnb[MSG + m];
    }
    // write bm per cell: bm_g[((b*NO1+no)*MSG+m)*NI1 + ni]
#pragma unroll
    for (int m = 0; m < MSG; m++)
        bm_g[(((size_t)b * NO1 + no) * MSG + m) * NI1 + ni] = bm[m];

    // write back state
#pragma unroll
    for (int s = 0; s < SLOW; s++) { h1g[s * SS + base] = h[s]; c1g[s * SS + base] = c[s]; }

    // reduce fm[0] over ni (128 threads)
    int lane = threadIdx.x & 63, wv = threadIdx.x >> 6;
    float v = fm[0];
#pragma unroll
    for (int d = 1; d < 64; d <<= 1) v += __shfl_xor(v, d);
    if (lane == 0) red[wv] = v;
    __syncthreads();
    if (threadIdx.x == 0) outsum[b * NO1 + no] = (red[0] + red[1]) * (1.f / NI1);
}

// ---------------------------------------------------------------------------
// nb1[b,ni,m] = mean over no of bm_g
// ---------------------------------------------------------------------------
__global__ void k_red1(const float* __restrict__ bm_g, float* __restrict__ nb1) {
    int g = blockIdx.x * 256 + threadIdx.x;  // < 8*128*16 = 16384
    int ni = g & 127;
    int m = (g >> 7) & 15;
    int b = g >> 11;
    float a = 0.f;
#pragma unroll 8
    for (int no = 0; no < NO1; no++)
        a += bm_g[(((size_t)b * NO1 + no) * MSG + m) * NI1 + ni];
    nb1[((size_t)b * NI1 + ni) * MSG + m] = a * (1.f / NO1);
}

// ---------------------------------------------------------------------------
// out/softmax/error: block per b (64 threads = classes)
// ---------------------------------------------------------------------------
__global__ void k_out(const float* __restrict__ outsum, const int* __restrict__ labels,
                      float* __restrict__ dout, float* __restrict__ gradP,
                      float* __restrict__ ohP, int t) {
    int b = blockIdx.x;
    int no = threadIdx.x;
    float v = outsum[b * NO1 + no];
    float mx = v;
#pragma unroll
    for (int d = 1; d < 64; d <<= 1) mx = fmaxf(mx, __shfl_xor(mx, d));
    float e = __expf(v - mx);
    float sum = e;
#pragma unroll
    for (int d = 1; d < 64; d <<= 1) sum += __shfl_xor(sum, d);
    int lbl = labels[t * BATCH + b];
    float oh = (no == lbl) ? 1.f : 0.f;
    gradP[b * NO1 + no] = e / sum - oh;
    ohP[b * NO1 + no] = oh;
    dout[((size_t)t * BATCH + b) * NO1 + no] = v;
}

// ---------------------------------------------------------------------------

extern "C" void kernel_launch(void* const* d_in, const int* in_sizes, int n_in,
                              void* d_out, int out_size, void* d_ws, size_t ws_size,
                              hipStream_t stream) {
    const float* inp   = (const float*)d_in[0];
    const int*   labels= (const int*)d_in[1];
    const float* Wi    = (const float*)d_in[2];
    const float* Wh    = (const float*)d_in[3];
    const float* b_lstm= (const float*)d_in[4];
    const float* Wf    = (const float*)d_in[5];
    const float* bf    = (const float*)d_in[6];
    const float* Wb    = (const float*)d_in[7];
    const float* bwb   = (const float*)d_in[8];
    const float* ln_fs = (const float*)d_in[9];
    const float* ln_fb = (const float*)d_in[10];
    const float* ln_bs = (const float*)d_in[11];
    const float* ln_bb = (const float*)d_in[12];
    float* out = (float*)d_out;

    float* w = (float*)d_ws;
    const size_t SZ_H0 = (size_t)SLOW * BATCH * NO0 * NI0;  // 8,388,608
    const size_t SZ_H1 = (size_t)SLOW * BATCH * NO1 * NI1;  // 2,097,152
    float* h0   = w;
    float* c0   = h0 + SZ_H0;
    float* h1   = c0 + SZ_H0;
    float* c1   = h1 + SZ_H1;
    float* xf1T = c1 + SZ_H1;                                 // 8*128*128
    float* bm_g = xf1T + (size_t)BATCH * 128 * NO0;           // 8*64*16*128
    float* nb1  = bm_g + (size_t)BATCH * NO1 * MSG * NI1;     // 8*128*16
    float* outsum = nb1 + (size_t)BATCH * NI1 * MSG;          // 512
    float* gradP  = outsum + BATCH * NO1;                     // 512
    float* ohP    = gradP + BATCH * NO1;                      // 512
    size_t total_floats = (size_t)(ohP - w) + BATCH * NO1;

    hipMemsetAsync(d_ws, 0, total_floats * sizeof(float), stream);

    for (int t = 0; t < TSTEPS; t++) {
        if (t) k_merge<<<2560, 256, 0, stream>>>(h0, c0, h1, c1);
        k_l0<<<BATCH * NO0, 256, 0, stream>>>(inp, Wi, Wh, b_lstm, Wf, bf, ln_fs, ln_fb,
                                              h0, c0, nb1, xf1T, t);
        k_l1<<<BATCH * NO1, 128, 0, stream>>>(Wi, Wh, b_lstm, Wf, bf, ln_fs, ln_fb,
                                              Wb, bwb, ln_bs, ln_bb,
                                              h1, c1, xf1T, gradP, ohP, bm_g, outsum);
        k_red1<<<64, 256, 0, stream>>>(bm_g, nb1);
        k_out<<<BATCH, NO1, 0, stream>>>(outsum, labels, out, gradP, ohP, t);
    }
}

// Round 2
// 2500.857 us; speedup vs baseline: 7.1396x; 7.1396x over previous
//
#include <hip/hip_runtime.h>
#include <hip/hip_bf16.h>

#define SLOW 32
#define MSG 16
#define TSTEPS 4
#define BATCH 8
#define NI0 256
#define NO0 128
#define NI1 128
#define NO1 64

__device__ __forceinline__ float sigf(float x) { return 1.f / (1.f + __expf(-x)); }
__device__ __forceinline__ float tanh_apx(float x) {
    float xc = fminf(fmaxf(x, -15.f), 15.f);
    float e = __expf(-2.f * xc);
    return (1.f - e) / (1.f + e);
}

// ---------------------------------------------------------------------------
// prep: transpose Wh (32x128) -> WhT (128x32), Wf/Wb (32x16) -> WfT/WbT (16x32)
// so each gate's weight row is contiguous -> uniform scalar (SMEM) loads
// ---------------------------------------------------------------------------
__global__ void k_prep(const float* __restrict__ Wh, const float* __restrict__ Wf,
                       const float* __restrict__ Wb,
                       float* __restrict__ WhT, float* __restrict__ WfT,
                       float* __restrict__ WbT) {
    int i = blockIdx.x * 256 + threadIdx.x;
    if (i < 128 * SLOW) {
        int j = i >> 7, k = i & 127;             // Wh[j*128+k]
        WhT[k * SLOW + j] = Wh[i];
    }
    if (i < MSG * SLOW) {
        int j = i >> 4, m = i & 15;              // Wf[j*16+m]
        WfT[m * SLOW + j] = Wf[i];
        WbT[m * SLOW + j] = Wb[i];
    }
}

// ---------------------------------------------------------------------------
// merge: for slow channels s<16, replace h/c with mean over batch (in place)
// layout of state: [s][b][no][ni]
// ---------------------------------------------------------------------------
__global__ void k_merge(float* __restrict__ h0, float* __restrict__ c0,
                        float* __restrict__ h1, float* __restrict__ c1) {
    int idx = blockIdx.x * blockDim.x + threadIdx.x;
    const int P0 = NO0 * NI0;
    const int P1 = NO1 * NI1;
    const int N0 = 16 * P0;
    const int N1 = 16 * P1;
    float* h; float* c; int s, p, plane;
    if (idx < N0) { h = h0; c = c0; s = idx / P0; p = idx % P0; plane = P0; }
    else {
        idx -= N0;
        if (idx >= N1) return;
        h = h1; c = c1; s = idx / P1; p = idx % P1; plane = P1;
    }
    size_t base = (size_t)(s * BATCH) * plane + p;
    float sh = 0.f, sc = 0.f;
#pragma unroll
    for (int b = 0; b < BATCH; b++) { sh += h[base + (size_t)b * plane]; sc += c[base + (size_t)b * plane]; }
    sh *= 0.125f; sc *= 0.125f;
#pragma unroll
    for (int b = 0; b < BATCH; b++) { h[base + (size_t)b * plane] = sh; c[base + (size_t)b * plane] = sc; }
}

// ---------------------------------------------------------------------------
// LSTM micro-iteration, weights via uniform scalar loads (SGPR), h/c in VGPRs
// ---------------------------------------------------------------------------
#define MICRO_ITER_L0(HI, HO)                                                  \
    do {                                                                       \
        _Pragma("unroll")                                                      \
        for (int s = 0; s < SLOW; s++) {                                       \
            const float* w0 = WhT + (s) * SLOW;                                \
            const float* w1 = WhT + (SLOW + s) * SLOW;                         \
            const float* w2 = WhT + (2 * SLOW + s) * SLOW;                     \
            const float* w3 = WhT + (3 * SLOW + s) * SLOW;                     \
            float a0 = gsh[s]            + mi * Wi[s];                         \
            float a1 = gsh[SLOW + s]     + mi * Wi[SLOW + s];                  \
            float a2 = gsh[2 * SLOW + s] + mi * Wi[2 * SLOW + s];              \
            float a3 = gsh[3 * SLOW + s] + mi * Wi[3 * SLOW + s];              \
            _Pragma("unroll")                                                  \
            for (int j = 0; j < SLOW; j++) {                                   \
                float x = HI[j];                                               \
                a0 += w0[j] * x; a1 += w1[j] * x;                              \
                a2 += w2[j] * x; a3 += w3[j] * x;                              \
            }                                                                  \
            float cg = tanh_apx(a2);                                           \
            float cn = sigf(a1) * c[s] + sigf(a0) * cg;                        \
            c[s] = cn;                                                         \
            HO[s] = sigf(a3) * tanh_apx(cn);                                   \
        }                                                                      \
    } while (0)

__global__ __launch_bounds__(256) void k_l0(
    const float* __restrict__ inp, const float* __restrict__ Wi,
    const float* __restrict__ WhT, const float* __restrict__ b_lstm,
    const float* __restrict__ WfT, const float* __restrict__ bf,
    const float* __restrict__ ln_fs, const float* __restrict__ ln_fb,
    float* __restrict__ h0g, float* __restrict__ c0g,
    const float* __restrict__ nb1, float* __restrict__ xf1T, int t) {
    int b = blockIdx.x >> 7;
    int no = blockIdx.x & 127;
    int ni = threadIdx.x;

    __shared__ float gsh[128];
    __shared__ float red[4][MSG];
    __shared__ float nfsh[MSG];

    if (threadIdx.x < 128) {
        int k = threadIdx.x;
        float acc = b_lstm[k];
        const float* nbr = nb1 + ((size_t)b * NO0 + no) * MSG;
#pragma unroll
        for (int m = 0; m < MSG; m++) acc += nbr[m] * Wi[(MSG + m) * 128 + k];
        gsh[k] = acc;
    }

    float mi = inp[((size_t)t * BATCH + b) * NI0 + ni];
    const size_t SS = (size_t)BATCH * NO0 * NI0;
    size_t base = ((size_t)b * NO0 + no) * NI0 + ni;

    float h[SLOW], hn[SLOW], c[SLOW];
#pragma unroll
    for (int s = 0; s < SLOW; s++) { h[s] = h0g[s * SS + base]; c[s] = c0g[s * SS + base]; }
    __syncthreads();

    MICRO_ITER_L0(h, hn);
    MICRO_ITER_L0(hn, h);

    // fm = LN(h @ Wf + bf)
    float fm[MSG];
#pragma unroll
    for (int m = 0; m < MSG; m++) {
        const float* w = WfT + m * SLOW;
        float a = bf[m];
#pragma unroll
        for (int j = 0; j < SLOW; j++) a += w[j] * h[j];
        fm[m] = a;
    }
    float mean = 0.f;
#pragma unroll
    for (int m = 0; m < MSG; m++) mean += fm[m];
    mean *= (1.f / MSG);
    float var = 0.f;
#pragma unroll
    for (int m = 0; m < MSG; m++) { float d = fm[m] - mean; var += d * d; }
    var *= (1.f / MSG);
    float rs = rsqrtf(var + 1e-6f);
#pragma unroll
    for (int m = 0; m < MSG; m++) fm[m] = (fm[m] - mean) * rs * ln_fs[m] + ln_fb[m];

    // write back state
#pragma unroll
    for (int s = 0; s < SLOW; s++) { h0g[s * SS + base] = h[s]; c0g[s * SS + base] = c[s]; }

    // reduce fm over ni (256 threads) -> nf[b,no,:]
    int lane = threadIdx.x & 63, wv = threadIdx.x >> 6;
#pragma unroll
    for (int m = 0; m < MSG; m++) {
        float v = fm[m];
#pragma unroll
        for (int d = 1; d < 64; d <<= 1) v += __shfl_xor(v, d);
        if (lane == 0) red[wv][m] = v;
    }
    __syncthreads();
    if (threadIdx.x < MSG) {
        int m = threadIdx.x;
        nfsh[m] = (red[0][m] + red[1][m] + red[2][m] + red[3][m]) * (1.f / NI0);
    }
    __syncthreads();
    // xf1T[b][k][no] = sum_m nf[m] * Wi[m,k]
    if (threadIdx.x < 128) {
        int k = threadIdx.x;
        float a = 0.f;
#pragma unroll
        for (int m = 0; m < MSG; m++) a += nfsh[m] * Wi[m * 128 + k];
        xf1T[((size_t)b * 128 + k) * NO0 + no] = a;
    }
}

#define MICRO_ITER_L1(HI, HO)                                                  \
    do {                                                                       \
        _Pragma("unroll")                                                      \
        for (int s = 0; s < SLOW; s++) {                                       \
            const float* w0 = WhT + (s) * SLOW;                                \
            const float* w1 = WhT + (SLOW + s) * SLOW;                         \
            const float* w2 = WhT + (2 * SLOW + s) * SLOW;                     \
            const float* w3 = WhT + (3 * SLOW + s) * SLOW;                     \
            float a0 = gsh[s]            + xfb[(s) * NI1 + ni];                \
            float a1 = gsh[SLOW + s]     + xfb[(SLOW + s) * NI1 + ni];         \
            float a2 = gsh[2 * SLOW + s] + xfb[(2 * SLOW + s) * NI1 + ni];     \
            float a3 = gsh[3 * SLOW + s] + xfb[(3 * SLOW + s) * NI1 + ni];     \
            _Pragma("unroll")                                                  \
            for (int j = 0; j < SLOW; j++) {                                   \
                float x = HI[j];                                               \
                a0 += w0[j] * x; a1 += w1[j] * x;                              \
                a2 += w2[j] * x; a3 += w3[j] * x;                              \
            }                                                                  \
            float cg = tanh_apx(a2);                                           \
            float cn = sigf(a1) * c[s] + sigf(a0) * cg;                        \
            c[s] = cn;                                                         \
            HO[s] = sigf(a3) * tanh_apx(cn);                                   \
        }                                                                      \
    } while (0)

__global__ __launch_bounds__(128) void k_l1(
    const float* __restrict__ Wi, const float* __restrict__ WhT,
    const float* __restrict__ b_lstm,
    const float* __restrict__ WfT, const float* __restrict__ bf,
    const float* __restrict__ ln_fs, const float* __restrict__ ln_fb,
    const float* __restrict__ WbT, const float* __restrict__ bwb,
    const float* __restrict__ ln_bs, const float* __restrict__ ln_bb,
    float* __restrict__ h1g, float* __restrict__ c1g,
    const float* __restrict__ xf1T, const float* __restrict__ gradP,
    const float* __restrict__ ohP,
    float* __restrict__ bm_g, float* __restrict__ outsum) {
    int b = blockIdx.x >> 6;
    int no = blockIdx.x & 63;
    int ni = threadIdx.x;

    __shared__ float gsh[128];
    __shared__ float red[2];

    {
        int k = threadIdx.x;  // 128 threads exactly
        float g = gradP[b * NO1 + no], oh = ohP[b * NO1 + no];
        gsh[k] = b_lstm[k] + g * Wi[MSG * 128 + k] + oh * Wi[(MSG + 1) * 128 + k];
    }

    const float* xfb = xf1T + (size_t)b * 128 * NI1;  // [k][ni]
    const size_t SS = (size_t)BATCH * NO1 * NI1;
    size_t base = ((size_t)b * NO1 + no) * NI1 + ni;

    float h[SLOW], hn[SLOW], c[SLOW];
#pragma unroll
    for (int s = 0; s < SLOW; s++) { h[s] = h1g[s * SS + base]; c[s] = c1g[s * SS + base]; }
    __syncthreads();

    MICRO_ITER_L1(h, hn);
    MICRO_ITER_L1(hn, h);

    // fm = LN(h@Wf+bf)
    float fm[MSG];
#pragma unroll
    for (int m = 0; m < MSG; m++) {
        const float* w = WfT + m * SLOW;
        float a = bf[m];
#pragma unroll
        for (int j = 0; j < SLOW; j++) a += w[j] * h[j];
        fm[m] = a;
    }
    {
        float mean = 0.f;
#pragma unroll
        for (int m = 0; m < MSG; m++) mean += fm[m];
        mean *= (1.f / MSG);
        float var = 0.f;
#pragma unroll
        for (int m = 0; m < MSG; m++) { float d = fm[m] - mean; var += d * d; }
        var *= (1.f / MSG);
        float rs = rsqrtf(var + 1e-6f);
#pragma unroll
        for (int m = 0; m < MSG; m++) fm[m] = (fm[m] - mean) * rs * ln_fs[m] + ln_fb[m];
    }
    // bm = LN(h@Wb+bwb)
    float bm[MSG];
#pragma unroll
    for (int m = 0; m < MSG; m++) {
        const float* w = WbT + m * SLOW;
        float a = bwb[m];
#pragma unroll
        for (int j = 0; j < SLOW; j++) a += w[j] * h[j];
        bm[m] = a;
    }
    {
        float mean = 0.f;
#pragma unroll
        for (int m = 0; m < MSG; m++) mean += bm[m];
        mean *= (1.f / MSG);
        float var = 0.f;
#pragma unroll
        for (int m = 0; m < MSG; m++) { float d = bm[m] - mean; var += d * d; }
        var *= (1.f / MSG);
        float rs = rsqrtf(var + 1e-6f);
#pragma unroll
        for (int m = 0; m < MSG; m++) bm[m] = (bm[m] - mean) * rs * ln_bs[m] + ln_bb[m];
    }
#pragma unroll
    for (int m = 0; m < MSG; m++)
        bm_g[(((size_t)b * NO1 + no) * MSG + m) * NI1 + ni] = bm[m];

    // write back state
#pragma unroll
    for (int s = 0; s < SLOW; s++) { h1g[s * SS + base] = h[s]; c1g[s * SS + base] = c[s]; }

    // reduce fm[0] over ni (128 threads)
    int lane = threadIdx.x & 63, wv = threadIdx.x >> 6;
    float v = fm[0];
#pragma unroll
    for (int d = 1; d < 64; d <<= 1) v += __shfl_xor(v, d);
    if (lane == 0) red[wv] = v;
    __syncthreads();
    if (threadIdx.x == 0) outsum[b * NO1 + no] = (red[0] + red[1]) * (1.f / NI1);
}

// ---------------------------------------------------------------------------
// nb1[b,ni,m] = mean over no of bm_g
// ---------------------------------------------------------------------------
__global__ void k_red1(const float* __restrict__ bm_g, float* __restrict__ nb1) {
    int g = blockIdx.x * 256 + threadIdx.x;  // < 8*128*16 = 16384
    int ni = g & 127;
    int m = (g >> 7) & 15;
    int b = g >> 11;
    float a = 0.f;
#pragma unroll 8
    for (int no = 0; no < NO1; no++)
        a += bm_g[(((size_t)b * NO1 + no) * MSG + m) * NI1 + ni];
    nb1[((size_t)b * NI1 + ni) * MSG + m] = a * (1.f / NO1);
}

// ---------------------------------------------------------------------------
// out/softmax/error: block per b (64 threads = classes)
// ---------------------------------------------------------------------------
__global__ void k_out(const float* __restrict__ outsum, const int* __restrict__ labels,
                      float* __restrict__ dout, float* __restrict__ gradP,
                      float* __restrict__ ohP, int t) {
    int b = blockIdx.x;
    int no = threadIdx.x;
    float v = outsum[b * NO1 + no];
    float mx = v;
#pragma unroll
    for (int d = 1; d < 64; d <<= 1) mx = fmaxf(mx, __shfl_xor(mx, d));
    float e = __expf(v - mx);
    float sum = e;
#pragma unroll
    for (int d = 1; d < 64; d <<= 1) sum += __shfl_xor(sum, d);
    int lbl = labels[t * BATCH + b];
    float oh = (no == lbl) ? 1.f : 0.f;
    gradP[b * NO1 + no] = e / sum - oh;
    ohP[b * NO1 + no] = oh;
    dout[((size_t)t * BATCH + b) * NO1 + no] = v;
}

// ---------------------------------------------------------------------------

extern "C" void kernel_launch(void* const* d_in, const int* in_sizes, int n_in,
                              void* d_out, int out_size, void* d_ws, size_t ws_size,
                              hipStream_t stream) {
    const float* inp   = (const float*)d_in[0];
    const int*   labels= (const int*)d_in[1];
    const float* Wi    = (const float*)d_in[2];
    const float* Wh    = (const float*)d_in[3];
    const float* b_lstm= (const float*)d_in[4];
    const float* Wf    = (const float*)d_in[5];
    const float* bf    = (const float*)d_in[6];
    const float* Wb    = (const float*)d_in[7];
    const float* bwb   = (const float*)d_in[8];
    const float* ln_fs = (const float*)d_in[9];
    const float* ln_fb = (const float*)d_in[10];
    const float* ln_bs = (const float*)d_in[11];
    const float* ln_bb = (const float*)d_in[12];
    float* out = (float*)d_out;

    float* w = (float*)d_ws;
    const size_t SZ_H0 = (size_t)SLOW * BATCH * NO0 * NI0;  // 8,388,608
    const size_t SZ_H1 = (size_t)SLOW * BATCH * NO1 * NI1;  // 2,097,152
    float* h0   = w;
    float* c0   = h0 + SZ_H0;
    float* h1   = c0 + SZ_H0;
    float* c1   = h1 + SZ_H1;
    float* xf1T = c1 + SZ_H1;                                 // 8*128*128
    float* bm_g = xf1T + (size_t)BATCH * 128 * NO0;           // 8*64*16*128
    float* nb1  = bm_g + (size_t)BATCH * NO1 * MSG * NI1;     // 8*128*16
    float* outsum = nb1 + (size_t)BATCH * NI1 * MSG;          // 512
    float* gradP  = outsum + BATCH * NO1;                     // 512
    float* ohP    = gradP + BATCH * NO1;                      // 512
    float* WhT    = ohP + BATCH * NO1;                        // 128*32
    float* WfT    = WhT + 128 * SLOW;                         // 16*32
    float* WbT    = WfT + MSG * SLOW;                         // 16*32
    size_t total_floats = (size_t)(WbT - w) + MSG * SLOW;

    hipMemsetAsync(d_ws, 0, total_floats * sizeof(float), stream);
    k_prep<<<16, 256, 0, stream>>>(Wh, Wf, Wb, WhT, WfT, WbT);

    for (int t = 0; t < TSTEPS; t++) {
        if (t) k_merge<<<2560, 256, 0, stream>>>(h0, c0, h1, c1);
        k_l0<<<BATCH * NO0, 256, 0, stream>>>(inp, Wi, WhT, b_lstm, WfT, bf, ln_fs, ln_fb,
                                              h0, c0, nb1, xf1T, t);
        k_l1<<<BATCH * NO1, 128, 0, stream>>>(Wi, WhT, b_lstm, WfT, bf, ln_fs, ln_fb,
                                              WbT, bwb, ln_bs, ln_bb,
                                              h1, c1, xf1T, gradP, ohP, bm_g, outsum);
        k_red1<<<64, 256, 0, stream>>>(bm_g, nb1);
        k_out<<<BATCH, NO1, 0, stream>>>(outsum, labels, out, gradP, ohP, t);
    }
}

// Round 3
// 1876.561 us; speedup vs baseline: 9.5148x; 1.3327x over previous
//
#include <hip/hip_runtime.h>
#include <hip/hip_bf16.h>

#define SLOW 32
#define MSG 16
#define TSTEPS 4
#define BATCH 8
#define NI0 256
#define NO0 128
#define NI1 128
#define NO1 64

__device__ __forceinline__ float sigf(float x) { return 1.f / (1.f + __expf(-x)); }
__device__ __forceinline__ float tanh_apx(float x) {
    float xc = fminf(fmaxf(x, -15.f), 15.f);
    float e = __expf(-2.f * xc);
    return (1.f - e) / (1.f + e);
}

// ---------------------------------------------------------------------------
// prep: transpose Wh (32x128) -> WhT (128x32), Wf/Wb (32x16) -> WfT/WbT (16x32)
// ---------------------------------------------------------------------------
__global__ void k_prep(const float* __restrict__ Wh, const float* __restrict__ Wf,
                       const float* __restrict__ Wb,
                       float* __restrict__ WhT, float* __restrict__ WfT,
                       float* __restrict__ WbT) {
    int i = blockIdx.x * 256 + threadIdx.x;
    if (i < 128 * SLOW) {
        int j = i >> 7, k = i & 127;
        WhT[k * SLOW + j] = Wh[i];
    }
    if (i < MSG * SLOW) {
        int j = i >> 4, m = i & 15;
        WfT[m * SLOW + j] = Wf[i];
        WbT[m * SLOW + j] = Wb[i];
    }
}

// ---------------------------------------------------------------------------
// merge: for slow channels s<16, replace h/c with mean over batch (in place)
// ---------------------------------------------------------------------------
__global__ void k_merge(float* __restrict__ h0, float* __restrict__ c0,
                        float* __restrict__ h1, float* __restrict__ c1) {
    int idx = blockIdx.x * blockDim.x + threadIdx.x;
    const int P0 = NO0 * NI0;
    const int P1 = NO1 * NI1;
    const int N0 = 16 * P0;
    const int N1 = 16 * P1;
    float* h; float* c; int s, p, plane;
    if (idx < N0) { h = h0; c = c0; s = idx / P0; p = idx % P0; plane = P0; }
    else {
        idx -= N0;
        if (idx >= N1) return;
        h = h1; c = c1; s = idx / P1; p = idx % P1; plane = P1;
    }
    size_t base = (size_t)(s * BATCH) * plane + p;
    float sh = 0.f, sc = 0.f;
#pragma unroll
    for (int b = 0; b < BATCH; b++) { sh += h[base + (size_t)b * plane]; sc += c[base + (size_t)b * plane]; }
    sh *= 0.125f; sc *= 0.125f;
#pragma unroll
    for (int b = 0; b < BATCH; b++) { h[base + (size_t)b * plane] = sh; c[base + (size_t)b * plane] = sc; }
}

// ---------------------------------------------------------------------------
// Layer 0: block = (b,no), 1024 threads = 4 s-groups x 256 cells.
// Thread (sg, cell) owns slow channels s = sg + 4k, k=0..7 (c[8] in regs).
// h shared across the cell's 4 threads via LDS [cell][33].
// ---------------------------------------------------------------------------
__global__ __launch_bounds__(1024) void k_l0(
    const float* __restrict__ inp, const float* __restrict__ Wi,
    const float* __restrict__ WhT, const float* __restrict__ b_lstm,
    const float* __restrict__ WfT, const float* __restrict__ bf,
    const float* __restrict__ ln_fs, const float* __restrict__ ln_fb,
    float* __restrict__ h0g, float* __restrict__ c0g,
    const float* __restrict__ nb1, float* __restrict__ xf1T, int t) {
    int b = blockIdx.x >> 7;
    int no = blockIdx.x & 127;
    int tid = threadIdx.x;
    int cell = tid & 255;
    int sgu = __builtin_amdgcn_readfirstlane(tid >> 8);  // wave-uniform s-group

    __shared__ float h_lds[256 * 33];
    __shared__ float fm_lds[256 * 17];
    __shared__ float gsh[128];
    __shared__ float red[16][MSG];
    __shared__ float nfsh[MSG];

    if (tid < 128) {
        int k = tid;
        float acc = b_lstm[k];
        const float* nbr = nb1 + ((size_t)b * NO0 + no) * MSG;
#pragma unroll
        for (int m = 0; m < MSG; m++) acc += nbr[m] * Wi[(MSG + m) * 128 + k];
        gsh[k] = acc;
    }

    float mi = inp[((size_t)t * BATCH + b) * NI0 + cell];
    const size_t SS = (size_t)BATCH * NO0 * NI0;
    size_t base = ((size_t)b * NO0 + no) * NI0 + cell;

    float c[8], hcur[8];
#pragma unroll
    for (int k = 0; k < 8; k++) {
        int s = sgu + 4 * k;
        hcur[k] = h0g[(size_t)s * SS + base];
        c[k] = c0g[(size_t)s * SS + base];
        h_lds[cell * 33 + s] = hcur[k];
    }
    __syncthreads();

    float hall[SLOW];
#pragma unroll
    for (int micro = 0; micro < 2; micro++) {
#pragma unroll
        for (int j = 0; j < SLOW; j++) hall[j] = h_lds[cell * 33 + j];
        __syncthreads();
#pragma unroll
        for (int k = 0; k < 8; k++) {
            int s = sgu + 4 * k;
            const float* w0 = WhT + s * SLOW;
            const float* w1 = WhT + (SLOW + s) * SLOW;
            const float* w2 = WhT + (2 * SLOW + s) * SLOW;
            const float* w3 = WhT + (3 * SLOW + s) * SLOW;
            float a0 = gsh[s] + mi * Wi[s];
            float a1 = gsh[SLOW + s] + mi * Wi[SLOW + s];
            float a2 = gsh[2 * SLOW + s] + mi * Wi[2 * SLOW + s];
            float a3 = gsh[3 * SLOW + s] + mi * Wi[3 * SLOW + s];
#pragma unroll
            for (int j = 0; j < SLOW; j++) {
                float x = hall[j];
                a0 += w0[j] * x; a1 += w1[j] * x;
                a2 += w2[j] * x; a3 += w3[j] * x;
            }
            float cn = sigf(a1) * c[k] + sigf(a0) * tanh_apx(a2);
            c[k] = cn;
            float hv = sigf(a3) * tanh_apx(cn);
            hcur[k] = hv;
            h_lds[cell * 33 + s] = hv;
        }
        __syncthreads();
    }

    // final h for fm
#pragma unroll
    for (int j = 0; j < SLOW; j++) hall[j] = h_lds[cell * 33 + j];

    // fm partial: this thread computes m = sgu*4 + mm
#pragma unroll
    for (int mm = 0; mm < 4; mm++) {
        int m = sgu * 4 + mm;
        const float* w = WfT + m * SLOW;
        float a = bf[m];
#pragma unroll
        for (int j = 0; j < SLOW; j++) a += w[j] * hall[j];
        fm_lds[cell * 17 + m] = a;
    }

    // state writeback (overlaps with fm exchange)
#pragma unroll
    for (int k = 0; k < 8; k++) {
        int s = sgu + 4 * k;
        h0g[(size_t)s * SS + base] = hcur[k];
        c0g[(size_t)s * SS + base] = c[k];
    }
    __syncthreads();

    float fm[MSG];
#pragma unroll
    for (int m = 0; m < MSG; m++) fm[m] = fm_lds[cell * 17 + m];
    float mean = 0.f;
#pragma unroll
    for (int m = 0; m < MSG; m++) mean += fm[m];
    mean *= (1.f / MSG);
    float var = 0.f;
#pragma unroll
    for (int m = 0; m < MSG; m++) { float d = fm[m] - mean; var += d * d; }
    var *= (1.f / MSG);
    float rs = rsqrtf(var + 1e-6f);
#pragma unroll
    for (int m = 0; m < MSG; m++) fm[m] = (fm[m] - mean) * rs * ln_fs[m] + ln_fb[m];

    // reduce over 1024 threads (each cell counted 4x -> /1024)
    int lane = tid & 63, wv = tid >> 6;
#pragma unroll
    for (int m = 0; m < MSG; m++) {
        float v = fm[m];
#pragma unroll
        for (int d = 1; d < 64; d <<= 1) v += __shfl_xor(v, d);
        if (lane == 0) red[wv][m] = v;
    }
    __syncthreads();
    if (tid < MSG) {
        float a = 0.f;
#pragma unroll
        for (int w = 0; w < 16; w++) a += red[w][tid];
        nfsh[tid] = a * (1.f / 1024.f);
    }
    __syncthreads();
    if (tid < 128) {
        int k = tid;
        float a = 0.f;
#pragma unroll
        for (int m = 0; m < MSG; m++) a += nfsh[m] * Wi[m * 128 + k];
        xf1T[((size_t)b * 128 + k) * NO0 + no] = a;
    }
}

// ---------------------------------------------------------------------------
// Layer 1: block = (b,no), 512 threads = 4 s-groups x 128 cells.
// ---------------------------------------------------------------------------
__global__ __launch_bounds__(512) void k_l1(
    const float* __restrict__ Wi, const float* __restrict__ WhT,
    const float* __restrict__ b_lstm,
    const float* __restrict__ WfT, const float* __restrict__ bf,
    const float* __restrict__ ln_fs, const float* __restrict__ ln_fb,
    const float* __restrict__ WbT, const float* __restrict__ bwb,
    const float* __restrict__ ln_bs, const float* __restrict__ ln_bb,
    float* __restrict__ h1g, float* __restrict__ c1g,
    const float* __restrict__ xf1T, const float* __restrict__ gradP,
    const float* __restrict__ ohP,
    float* __restrict__ bm_g, float* __restrict__ outsum) {
    int b = blockIdx.x >> 6;
    int no = blockIdx.x & 63;
    int tid = threadIdx.x;
    int cell = tid & 127;
    int sgu = __builtin_amdgcn_readfirstlane(tid >> 7);

    __shared__ float h_lds[128 * 33];
    __shared__ float msg_lds[128 * 17];
    __shared__ float gsh[128];
    __shared__ float red[8];

    if (tid < 128) {
        int k = tid;
        float g = gradP[b * NO1 + no], oh = ohP[b * NO1 + no];
        gsh[k] = b_lstm[k] + g * Wi[MSG * 128 + k] + oh * Wi[(MSG + 1) * 128 + k];
    }

    const float* xfb = xf1T + (size_t)b * 128 * NI1;  // [gate][ni]
    const size_t SS = (size_t)BATCH * NO1 * NI1;
    size_t base = ((size_t)b * NO1 + no) * NI1 + cell;

    // preload this thread's input-gate terms: 4 gates x 8 s
    float xf0[8], xf1[8], xf2[8], xf3[8];
#pragma unroll
    for (int k = 0; k < 8; k++) {
        int s = sgu + 4 * k;
        xf0[k] = xfb[s * NI1 + cell];
        xf1[k] = xfb[(SLOW + s) * NI1 + cell];
        xf2[k] = xfb[(2 * SLOW + s) * NI1 + cell];
        xf3[k] = xfb[(3 * SLOW + s) * NI1 + cell];
    }

    float c[8], hcur[8];
#pragma unroll
    for (int k = 0; k < 8; k++) {
        int s = sgu + 4 * k;
        hcur[k] = h1g[(size_t)s * SS + base];
        c[k] = c1g[(size_t)s * SS + base];
        h_lds[cell * 33 + s] = hcur[k];
    }
    __syncthreads();

    float hall[SLOW];
#pragma unroll
    for (int micro = 0; micro < 2; micro++) {
#pragma unroll
        for (int j = 0; j < SLOW; j++) hall[j] = h_lds[cell * 33 + j];
        __syncthreads();
#pragma unroll
        for (int k = 0; k < 8; k++) {
            int s = sgu + 4 * k;
            const float* w0 = WhT + s * SLOW;
            const float* w1 = WhT + (SLOW + s) * SLOW;
            const float* w2 = WhT + (2 * SLOW + s) * SLOW;
            const float* w3 = WhT + (3 * SLOW + s) * SLOW;
            float a0 = gsh[s] + xf0[k];
            float a1 = gsh[SLOW + s] + xf1[k];
            float a2 = gsh[2 * SLOW + s] + xf2[k];
            float a3 = gsh[3 * SLOW + s] + xf3[k];
#pragma unroll
            for (int j = 0; j < SLOW; j++) {
                float x = hall[j];
                a0 += w0[j] * x; a1 += w1[j] * x;
                a2 += w2[j] * x; a3 += w3[j] * x;
            }
            float cn = sigf(a1) * c[k] + sigf(a0) * tanh_apx(a2);
            c[k] = cn;
            float hv = sigf(a3) * tanh_apx(cn);
            hcur[k] = hv;
            h_lds[cell * 33 + s] = hv;
        }
        __syncthreads();
    }

#pragma unroll
    for (int j = 0; j < SLOW; j++) hall[j] = h_lds[cell * 33 + j];

    // ---- fm (need LN'd channel 0) ----
#pragma unroll
    for (int mm = 0; mm < 4; mm++) {
        int m = sgu * 4 + mm;
        const float* w = WfT + m * SLOW;
        float a = bf[m];
#pragma unroll
        for (int j = 0; j < SLOW; j++) a += w[j] * hall[j];
        msg_lds[cell * 17 + m] = a;
    }

    // state writeback
#pragma unroll
    for (int k = 0; k < 8; k++) {
        int s = sgu + 4 * k;
        h1g[(size_t)s * SS + base] = hcur[k];
        c1g[(size_t)s * SS + base] = c[k];
    }
    __syncthreads();

    float fm0;
    {
        float fmv[MSG];
#pragma unroll
        for (int m = 0; m < MSG; m++) fmv[m] = msg_lds[cell * 17 + m];
        float mean = 0.f;
#pragma unroll
        for (int m = 0; m < MSG; m++) mean += fmv[m];
        mean *= (1.f / MSG);
        float var = 0.f;
#pragma unroll
        for (int m = 0; m < MSG; m++) { float d = fmv[m] - mean; var += d * d; }
        var *= (1.f / MSG);
        float rs = rsqrtf(var + 1e-6f);
        fm0 = (fmv[0] - mean) * rs * ln_fs[0] + ln_fb[0];
    }
    __syncthreads();  // msg_lds reads done before bm overwrites

    // ---- bm ----
#pragma unroll
    for (int mm = 0; mm < 4; mm++) {
        int m = sgu * 4 + mm;
        const float* w = WbT + m * SLOW;
        float a = bwb[m];
#pragma unroll
        for (int j = 0; j < SLOW; j++) a += w[j] * hall[j];
        msg_lds[cell * 17 + m] = a;
    }
    __syncthreads();
    {
        float bmv[MSG];
#pragma unroll
        for (int m = 0; m < MSG; m++) bmv[m] = msg_lds[cell * 17 + m];
        float mean = 0.f;
#pragma unroll
        for (int m = 0; m < MSG; m++) mean += bmv[m];
        mean *= (1.f / MSG);
        float var = 0.f;
#pragma unroll
        for (int m = 0; m < MSG; m++) { float d = bmv[m] - mean; var += d * d; }
        var *= (1.f / MSG);
        float rs = rsqrtf(var + 1e-6f);
#pragma unroll
        for (int m = 0; m < MSG; m++) bmv[m] = (bmv[m] - mean) * rs * ln_bs[m] + ln_bb[m];
        // each sg writes its 4 m-planes (coalesced over cells)
#pragma unroll
        for (int mm = 0; mm < 4; mm++) {
            int m = sgu * 4 + mm;
            bm_g[(((size_t)b * NO1 + no) * MSG + m) * NI1 + cell] = bmv[m];
        }
    }

    // outsum: mean over cells of fm0 (each cell counted 4x -> /512)
    int lane = tid & 63, wv = tid >> 6;
    float v = fm0;
#pragma unroll
    for (int d = 1; d < 64; d <<= 1) v += __shfl_xor(v, d);
    if (lane == 0) red[wv] = v;
    __syncthreads();
    if (tid == 0) {
        float a = 0.f;
#pragma unroll
        for (int w = 0; w < 8; w++) a += red[w];
        outsum[b * NO1 + no] = a * (1.f / 512.f);
    }
}

// ---------------------------------------------------------------------------
// nb1[b,ni,m] = mean over no of bm_g
// ---------------------------------------------------------------------------
__global__ void k_red1(const float* __restrict__ bm_g, float* __restrict__ nb1) {
    int g = blockIdx.x * 256 + threadIdx.x;  // < 8*128*16 = 16384
    int ni = g & 127;
    int m = (g >> 7) & 15;
    int b = g >> 11;
    float a = 0.f;
#pragma unroll 8
    for (int no = 0; no < NO1; no++)
        a += bm_g[(((size_t)b * NO1 + no) * MSG + m) * NI1 + ni];
    nb1[((size_t)b * NI1 + ni) * MSG + m] = a * (1.f / NO1);
}

// ---------------------------------------------------------------------------
// out/softmax/error
// ---------------------------------------------------------------------------
__global__ void k_out(const float* __restrict__ outsum, const int* __restrict__ labels,
                      float* __restrict__ dout, float* __restrict__ gradP,
                      float* __restrict__ ohP, int t) {
    int b = blockIdx.x;
    int no = threadIdx.x;
    float v = outsum[b * NO1 + no];
    float mx = v;
#pragma unroll
    for (int d = 1; d < 64; d <<= 1) mx = fmaxf(mx, __shfl_xor(mx, d));
    float e = __expf(v - mx);
    float sum = e;
#pragma unroll
    for (int d = 1; d < 64; d <<= 1) sum += __shfl_xor(sum, d);
    int lbl = labels[t * BATCH + b];
    float oh = (no == lbl) ? 1.f : 0.f;
    gradP[b * NO1 + no] = e / sum - oh;
    ohP[b * NO1 + no] = oh;
    dout[((size_t)t * BATCH + b) * NO1 + no] = v;
}

// ---------------------------------------------------------------------------

extern "C" void kernel_launch(void* const* d_in, const int* in_sizes, int n_in,
                              void* d_out, int out_size, void* d_ws, size_t ws_size,
                              hipStream_t stream) {
    const float* inp   = (const float*)d_in[0];
    const int*   labels= (const int*)d_in[1];
    const float* Wi    = (const float*)d_in[2];
    const float* Wh    = (const float*)d_in[3];
    const float* b_lstm= (const float*)d_in[4];
    const float* Wf    = (const float*)d_in[5];
    const float* bf    = (const float*)d_in[6];
    const float* Wb    = (const float*)d_in[7];
    const float* bwb   = (const float*)d_in[8];
    const float* ln_fs = (const float*)d_in[9];
    const float* ln_fb = (const float*)d_in[10];
    const float* ln_bs = (const float*)d_in[11];
    const float* ln_bb = (const float*)d_in[12];
    float* out = (float*)d_out;

    float* w = (float*)d_ws;
    const size_t SZ_H0 = (size_t)SLOW * BATCH * NO0 * NI0;  // 8,388,608
    const size_t SZ_H1 = (size_t)SLOW * BATCH * NO1 * NI1;  // 2,097,152
    float* h0   = w;
    float* c0   = h0 + SZ_H0;
    float* h1   = c0 + SZ_H0;
    float* c1   = h1 + SZ_H1;
    float* xf1T = c1 + SZ_H1;                                 // 8*128*128
    float* bm_g = xf1T + (size_t)BATCH * 128 * NO0;           // 8*64*16*128
    float* nb1  = bm_g + (size_t)BATCH * NO1 * MSG * NI1;     // 8*128*16
    float* outsum = nb1 + (size_t)BATCH * NI1 * MSG;          // 512
    float* gradP  = outsum + BATCH * NO1;                     // 512
    float* ohP    = gradP + BATCH * NO1;                      // 512
    float* WhT    = ohP + BATCH * NO1;                        // 128*32
    float* WfT    = WhT + 128 * SLOW;                         // 16*32
    float* WbT    = WfT + MSG * SLOW;                         // 16*32
    size_t total_floats = (size_t)(WbT - w) + MSG * SLOW;

    hipMemsetAsync(d_ws, 0, total_floats * sizeof(float), stream);
    k_prep<<<16, 256, 0, stream>>>(Wh, Wf, Wb, WhT, WfT, WbT);

    for (int t = 0; t < TSTEPS; t++) {
        if (t) k_merge<<<2560, 256, 0, stream>>>(h0, c0, h1, c1);
        k_l0<<<BATCH * NO0, 1024, 0, stream>>>(inp, Wi, WhT, b_lstm, WfT, bf, ln_fs, ln_fb,
                                               h0, c0, nb1, xf1T, t);
        k_l1<<<BATCH * NO1, 512, 0, stream>>>(Wi, WhT, b_lstm, WfT, bf, ln_fs, ln_fb,
                                              WbT, bwb, ln_bs, ln_bb,
                                              h1, c1, xf1T, gradP, ohP, bm_g, outsum);
        k_red1<<<64, 256, 0, stream>>>(bm_g, nb1);
        k_out<<<BATCH, NO1, 0, stream>>>(outsum, labels, out, gradP, ohP, t);
    }
}

// Round 4
// 1462.644 us; speedup vs baseline: 12.2074x; 1.2830x over previous
//
#include <hip/hip_runtime.h>
#include <hip/hip_bf16.h>

#define SLOW 32
#define MSG 16
#define TSTEPS 4
#define BATCH 8
#define NI0 256
#define NO0 128
#define NI1 128
#define NO1 64

__device__ __forceinline__ float sigf(float x) { return 1.f / (1.f + __expf(-x)); }
__device__ __forceinline__ float tanh_apx(float x) {
    float xc = fminf(fmaxf(x, -15.f), 15.f);
    float e = __expf(-2.f * xc);
    return (1.f - e) / (1.f + e);
}

// ---------------------------------------------------------------------------
// prep: transpose Wh (32x128) -> WhT (128x32), Wf/Wb (32x16) -> WfT/WbT (16x32)
// ---------------------------------------------------------------------------
__global__ void k_prep(const float* __restrict__ Wh, const float* __restrict__ Wf,
                       const float* __restrict__ Wb,
                       float* __restrict__ WhT, float* __restrict__ WfT,
                       float* __restrict__ WbT) {
    int i = blockIdx.x * 256 + threadIdx.x;
    if (i < 128 * SLOW) {
        int j = i >> 7, k = i & 127;
        WhT[k * SLOW + j] = Wh[i];
    }
    if (i < MSG * SLOW) {
        int j = i >> 4, m = i & 15;
        WfT[m * SLOW + j] = Wf[i];
        WbT[m * SLOW + j] = Wb[i];
    }
}

// ---------------------------------------------------------------------------
// merge: for slow channels s<16, replace h/c with mean over batch (in place)
// ---------------------------------------------------------------------------
__global__ void k_merge(float* __restrict__ h0, float* __restrict__ c0,
                        float* __restrict__ h1, float* __restrict__ c1) {
    int idx = blockIdx.x * blockDim.x + threadIdx.x;
    const int P0 = NO0 * NI0;
    const int P1 = NO1 * NI1;
    const int N0 = 16 * P0;
    const int N1 = 16 * P1;
    float* h; float* c; int s, p, plane;
    if (idx < N0) { h = h0; c = c0; s = idx / P0; p = idx % P0; plane = P0; }
    else {
        idx -= N0;
        if (idx >= N1) return;
        h = h1; c = c1; s = idx / P1; p = idx % P1; plane = P1;
    }
    size_t base = (size_t)(s * BATCH) * plane + p;
    float sh = 0.f, sc = 0.f;
#pragma unroll
    for (int b = 0; b < BATCH; b++) { sh += h[base + (size_t)b * plane]; sc += c[base + (size_t)b * plane]; }
    sh *= 0.125f; sc *= 0.125f;
#pragma unroll
    for (int b = 0; b < BATCH; b++) { h[base + (size_t)b * plane] = sh; c[base + (size_t)b * plane] = sc; }
}

// ---------------------------------------------------------------------------
// Layer 0: block = (b,no,quarter), 256 threads = 4 s-groups x 64 cells.
// Thread (sg, cell) owns slow channels s = sg + 4k, k=0..7.
// Writes raw fm partial sums to nf_part[b][no][q][m] (summed in k_xf).
// ---------------------------------------------------------------------------
__global__ __launch_bounds__(256) void k_l0(
    const float* __restrict__ inp, const float* __restrict__ Wi,
    const float* __restrict__ WhT, const float* __restrict__ b_lstm,
    const float* __restrict__ WfT, const float* __restrict__ bf,
    const float* __restrict__ ln_fs, const float* __restrict__ ln_fb,
    float* __restrict__ h0g, float* __restrict__ c0g,
    const float* __restrict__ nb1, float* __restrict__ nf_part, int t) {
    int q = blockIdx.x & 3;
    int no = (blockIdx.x >> 2) & 127;
    int b = blockIdx.x >> 9;
    int tid = threadIdx.x;
    int cl = tid & 63;                                   // local cell
    int sgu = __builtin_amdgcn_readfirstlane(tid >> 6);  // wave-uniform s-group
    int cell = q * 64 + cl;

    __shared__ float h_lds[64 * 33];
    __shared__ float fm_lds[64 * 17];
    __shared__ float gsh[128];
    __shared__ float red[4][MSG];

    if (tid < 128) {
        int k = tid;
        float acc = b_lstm[k];
        const float* nbr = nb1 + ((size_t)b * NO0 + no) * MSG;
#pragma unroll
        for (int m = 0; m < MSG; m++) acc += nbr[m] * Wi[(MSG + m) * 128 + k];
        gsh[k] = acc;
    }

    float mi = inp[((size_t)t * BATCH + b) * NI0 + cell];
    const size_t SS = (size_t)BATCH * NO0 * NI0;
    size_t base = ((size_t)b * NO0 + no) * NI0 + cell;

    float c[8], hcur[8];
#pragma unroll
    for (int k = 0; k < 8; k++) {
        int s = sgu + 4 * k;
        hcur[k] = h0g[(size_t)s * SS + base];
        c[k] = c0g[(size_t)s * SS + base];
        h_lds[cl * 33 + s] = hcur[k];
    }
    __syncthreads();

    float hall[SLOW];
#pragma unroll
    for (int micro = 0; micro < 2; micro++) {
#pragma unroll
        for (int j = 0; j < SLOW; j++) hall[j] = h_lds[cl * 33 + j];
        __syncthreads();
#pragma unroll
        for (int k = 0; k < 8; k++) {
            int s = sgu + 4 * k;
            const float* w0 = WhT + s * SLOW;
            const float* w1 = WhT + (SLOW + s) * SLOW;
            const float* w2 = WhT + (2 * SLOW + s) * SLOW;
            const float* w3 = WhT + (3 * SLOW + s) * SLOW;
            float a0 = gsh[s] + mi * Wi[s];
            float a1 = gsh[SLOW + s] + mi * Wi[SLOW + s];
            float a2 = gsh[2 * SLOW + s] + mi * Wi[2 * SLOW + s];
            float a3 = gsh[3 * SLOW + s] + mi * Wi[3 * SLOW + s];
#pragma unroll
            for (int j = 0; j < SLOW; j++) {
                float x = hall[j];
                a0 += w0[j] * x; a1 += w1[j] * x;
                a2 += w2[j] * x; a3 += w3[j] * x;
            }
            float cn = sigf(a1) * c[k] + sigf(a0) * tanh_apx(a2);
            c[k] = cn;
            float hv = sigf(a3) * tanh_apx(cn);
            hcur[k] = hv;
            h_lds[cl * 33 + s] = hv;
        }
        __syncthreads();
    }

#pragma unroll
    for (int j = 0; j < SLOW; j++) hall[j] = h_lds[cl * 33 + j];

    // fm partial: this thread computes m = sgu*4 + mm
#pragma unroll
    for (int mm = 0; mm < 4; mm++) {
        int m = sgu * 4 + mm;
        const float* w = WfT + m * SLOW;
        float a = bf[m];
#pragma unroll
        for (int j = 0; j < SLOW; j++) a += w[j] * hall[j];
        fm_lds[cl * 17 + m] = a;
    }

    // state writeback (overlaps with fm exchange)
#pragma unroll
    for (int k = 0; k < 8; k++) {
        int s = sgu + 4 * k;
        h0g[(size_t)s * SS + base] = hcur[k];
        c0g[(size_t)s * SS + base] = c[k];
    }
    __syncthreads();

    float fm[MSG];
#pragma unroll
    for (int m = 0; m < MSG; m++) fm[m] = fm_lds[cl * 17 + m];
    float mean = 0.f;
#pragma unroll
    for (int m = 0; m < MSG; m++) mean += fm[m];
    mean *= (1.f / MSG);
    float var = 0.f;
#pragma unroll
    for (int m = 0; m < MSG; m++) { float d = fm[m] - mean; var += d * d; }
    var *= (1.f / MSG);
    float rs = rsqrtf(var + 1e-6f);
#pragma unroll
    for (int m = 0; m < MSG; m++) fm[m] = (fm[m] - mean) * rs * ln_fs[m] + ln_fb[m];

    // raw partial sum over the block's 256 threads (each cell counted 4x)
    int lane = tid & 63, wv = tid >> 6;
#pragma unroll
    for (int m = 0; m < MSG; m++) {
        float v = fm[m];
#pragma unroll
        for (int d = 1; d < 64; d <<= 1) v += __shfl_xor(v, d);
        if (lane == 0) red[wv][m] = v;
    }
    __syncthreads();
    if (tid < MSG) {
        float a = red[0][tid] + red[1][tid] + red[2][tid] + red[3][tid];
        nf_part[(((size_t)b * NO0 + no) * 4 + q) * MSG + tid] = a;
    }
}

// ---------------------------------------------------------------------------
// k_xf: xf1T[b][k][no0] = sum_m nf[b,no0,m] * Wi[m,k], nf = sum_q part / 1024
// block = (b,k) [1024 blocks], threads = no0 (128)
// ---------------------------------------------------------------------------
__global__ __launch_bounds__(128) void k_xf(const float* __restrict__ nf_part,
                                            const float* __restrict__ Wi,
                                            float* __restrict__ xf1T) {
    int b = blockIdx.x >> 7;
    int k = blockIdx.x & 127;
    int no = threadIdx.x;
    float nf[MSG];
#pragma unroll
    for (int m = 0; m < MSG; m++) nf[m] = 0.f;
    const float* p = nf_part + ((size_t)b * NO0 + no) * 4 * MSG;
#pragma unroll
    for (int qm = 0; qm < 4 * MSG; qm++) nf[qm & 15] += p[qm];
    float a = 0.f;
#pragma unroll
    for (int m = 0; m < MSG; m++) a += nf[m] * Wi[m * 128 + k];
    xf1T[((size_t)b * 128 + k) * NO0 + no] = a * (1.f / 1024.f);
}

// ---------------------------------------------------------------------------
// Layer 1: block = (b,no,half), 256 threads = 4 s-groups x 64 cells.
// ---------------------------------------------------------------------------
__global__ __launch_bounds__(256) void k_l1(
    const float* __restrict__ Wi, const float* __restrict__ WhT,
    const float* __restrict__ b_lstm,
    const float* __restrict__ WfT, const float* __restrict__ bf,
    const float* __restrict__ ln_fs, const float* __restrict__ ln_fb,
    const float* __restrict__ WbT, const float* __restrict__ bwb,
    const float* __restrict__ ln_bs, const float* __restrict__ ln_bb,
    float* __restrict__ h1g, float* __restrict__ c1g,
    const float* __restrict__ xf1T, const float* __restrict__ gradP,
    const float* __restrict__ ohP,
    float* __restrict__ bm_g, float* __restrict__ outsum_part) {
    int q = blockIdx.x & 1;
    int no = (blockIdx.x >> 1) & 63;
    int b = blockIdx.x >> 7;
    int tid = threadIdx.x;
    int cl = tid & 63;
    int sgu = __builtin_amdgcn_readfirstlane(tid >> 6);
    int cell = q * 64 + cl;

    __shared__ float h_lds[64 * 33];
    __shared__ float msg_lds[64 * 17];
    __shared__ float gsh[128];
    __shared__ float red[4];

    if (tid < 128) {
        int k = tid;
        float g = gradP[b * NO1 + no], oh = ohP[b * NO1 + no];
        gsh[k] = b_lstm[k] + g * Wi[MSG * 128 + k] + oh * Wi[(MSG + 1) * 128 + k];
    }

    const float* xfb = xf1T + (size_t)b * 128 * NI1;  // [gate][ni]
    const size_t SS = (size_t)BATCH * NO1 * NI1;
    size_t base = ((size_t)b * NO1 + no) * NI1 + cell;

    float xf0[8], xf1[8], xf2[8], xf3[8];
#pragma unroll
    for (int k = 0; k < 8; k++) {
        int s = sgu + 4 * k;
        xf0[k] = xfb[s * NI1 + cell];
        xf1[k] = xfb[(SLOW + s) * NI1 + cell];
        xf2[k] = xfb[(2 * SLOW + s) * NI1 + cell];
        xf3[k] = xfb[(3 * SLOW + s) * NI1 + cell];
    }

    float c[8], hcur[8];
#pragma unroll
    for (int k = 0; k < 8; k++) {
        int s = sgu + 4 * k;
        hcur[k] = h1g[(size_t)s * SS + base];
        c[k] = c1g[(size_t)s * SS + base];
        h_lds[cl * 33 + s] = hcur[k];
    }
    __syncthreads();

    float hall[SLOW];
#pragma unroll
    for (int micro = 0; micro < 2; micro++) {
#pragma unroll
        for (int j = 0; j < SLOW; j++) hall[j] = h_lds[cl * 33 + j];
        __syncthreads();
#pragma unroll
        for (int k = 0; k < 8; k++) {
            int s = sgu + 4 * k;
            const float* w0 = WhT + s * SLOW;
            const float* w1 = WhT + (SLOW + s) * SLOW;
            const float* w2 = WhT + (2 * SLOW + s) * SLOW;
            const float* w3 = WhT + (3 * SLOW + s) * SLOW;
            float a0 = gsh[s] + xf0[k];
            float a1 = gsh[SLOW + s] + xf1[k];
            float a2 = gsh[2 * SLOW + s] + xf2[k];
            float a3 = gsh[3 * SLOW + s] + xf3[k];
#pragma unroll
            for (int j = 0; j < SLOW; j++) {
                float x = hall[j];
                a0 += w0[j] * x; a1 += w1[j] * x;
                a2 += w2[j] * x; a3 += w3[j] * x;
            }
            float cn = sigf(a1) * c[k] + sigf(a0) * tanh_apx(a2);
            c[k] = cn;
            float hv = sigf(a3) * tanh_apx(cn);
            hcur[k] = hv;
            h_lds[cl * 33 + s] = hv;
        }
        __syncthreads();
    }

#pragma unroll
    for (int j = 0; j < SLOW; j++) hall[j] = h_lds[cl * 33 + j];

    // ---- fm (need LN'd channel 0) ----
#pragma unroll
    for (int mm = 0; mm < 4; mm++) {
        int m = sgu * 4 + mm;
        const float* w = WfT + m * SLOW;
        float a = bf[m];
#pragma unroll
        for (int j = 0; j < SLOW; j++) a += w[j] * hall[j];
        msg_lds[cl * 17 + m] = a;
    }

    // state writeback
#pragma unroll
    for (int k = 0; k < 8; k++) {
        int s = sgu + 4 * k;
        h1g[(size_t)s * SS + base] = hcur[k];
        c1g[(size_t)s * SS + base] = c[k];
    }
    __syncthreads();

    float fm0;
    {
        float fmv[MSG];
#pragma unroll
        for (int m = 0; m < MSG; m++) fmv[m] = msg_lds[cl * 17 + m];
        float mean = 0.f;
#pragma unroll
        for (int m = 0; m < MSG; m++) mean += fmv[m];
        mean *= (1.f / MSG);
        float var = 0.f;
#pragma unroll
        for (int m = 0; m < MSG; m++) { float d = fmv[m] - mean; var += d * d; }
        var *= (1.f / MSG);
        float rs = rsqrtf(var + 1e-6f);
        fm0 = (fmv[0] - mean) * rs * ln_fs[0] + ln_fb[0];
    }
    __syncthreads();  // msg_lds reads done before bm overwrites

    // ---- bm ----
#pragma unroll
    for (int mm = 0; mm < 4; mm++) {
        int m = sgu * 4 + mm;
        const float* w = WbT + m * SLOW;
        float a = bwb[m];
#pragma unroll
        for (int j = 0; j < SLOW; j++) a += w[j] * hall[j];
        msg_lds[cl * 17 + m] = a;
    }
    __syncthreads();
    {
        float bmv[MSG];
#pragma unroll
        for (int m = 0; m < MSG; m++) bmv[m] = msg_lds[cl * 17 + m];
        float mean = 0.f;
#pragma unroll
        for (int m = 0; m < MSG; m++) mean += bmv[m];
        mean *= (1.f / MSG);
        float var = 0.f;
#pragma unroll
        for (int m = 0; m < MSG; m++) { float d = bmv[m] - mean; var += d * d; }
        var *= (1.f / MSG);
        float rs = rsqrtf(var + 1e-6f);
#pragma unroll
        for (int m = 0; m < MSG; m++) bmv[m] = (bmv[m] - mean) * rs * ln_bs[m] + ln_bb[m];
#pragma unroll
        for (int mm = 0; mm < 4; mm++) {
            int m = sgu * 4 + mm;
            bm_g[(((size_t)b * NO1 + no) * MSG + m) * NI1 + cell] = bmv[m];
        }
    }

    // raw partial sum of fm0 over block (each cell counted 4x)
    int lane = tid & 63, wv = tid >> 6;
    float v = fm0;
#pragma unroll
    for (int d = 1; d < 64; d <<= 1) v += __shfl_xor(v, d);
    if (lane == 0) red[wv] = v;
    __syncthreads();
    if (tid == 0)
        outsum_part[((size_t)b * NO1 + no) * 2 + q] = red[0] + red[1] + red[2] + red[3];
}

// ---------------------------------------------------------------------------
// nb1[b,ni,m] = mean over no of bm_g
// ---------------------------------------------------------------------------
__global__ void k_red1(const float* __restrict__ bm_g, float* __restrict__ nb1) {
    int g = blockIdx.x * 256 + threadIdx.x;  // < 8*128*16 = 16384
    int ni = g & 127;
    int m = (g >> 7) & 15;
    int b = g >> 11;
    float a = 0.f;
#pragma unroll 8
    for (int no = 0; no < NO1; no++)
        a += bm_g[(((size_t)b * NO1 + no) * MSG + m) * NI1 + ni];
    nb1[((size_t)b * NI1 + ni) * MSG + m] = a * (1.f / NO1);
}

// ---------------------------------------------------------------------------
// out/softmax/error: block per b (64 threads = classes)
// ---------------------------------------------------------------------------
__global__ void k_out(const float* __restrict__ outsum_part, const int* __restrict__ labels,
                      float* __restrict__ dout, float* __restrict__ gradP,
                      float* __restrict__ ohP, int t) {
    int b = blockIdx.x;
    int no = threadIdx.x;
    float v = (outsum_part[((size_t)b * NO1 + no) * 2] +
               outsum_part[((size_t)b * NO1 + no) * 2 + 1]) * (1.f / 512.f);
    float mx = v;
#pragma unroll
    for (int d = 1; d < 64; d <<= 1) mx = fmaxf(mx, __shfl_xor(mx, d));
    float e = __expf(v - mx);
    float sum = e;
#pragma unroll
    for (int d = 1; d < 64; d <<= 1) sum += __shfl_xor(sum, d);
    int lbl = labels[t * BATCH + b];
    float oh = (no == lbl) ? 1.f : 0.f;
    gradP[b * NO1 + no] = e / sum - oh;
    ohP[b * NO1 + no] = oh;
    dout[((size_t)t * BATCH + b) * NO1 + no] = v;
}

// ---------------------------------------------------------------------------

extern "C" void kernel_launch(void* const* d_in, const int* in_sizes, int n_in,
                              void* d_out, int out_size, void* d_ws, size_t ws_size,
                              hipStream_t stream) {
    const float* inp   = (const float*)d_in[0];
    const int*   labels= (const int*)d_in[1];
    const float* Wi    = (const float*)d_in[2];
    const float* Wh    = (const float*)d_in[3];
    const float* b_lstm= (const float*)d_in[4];
    const float* Wf    = (const float*)d_in[5];
    const float* bf    = (const float*)d_in[6];
    const float* Wb    = (const float*)d_in[7];
    const float* bwb   = (const float*)d_in[8];
    const float* ln_fs = (const float*)d_in[9];
    const float* ln_fb = (const float*)d_in[10];
    const float* ln_bs = (const float*)d_in[11];
    const float* ln_bb = (const float*)d_in[12];
    float* out = (float*)d_out;

    float* w = (float*)d_ws;
    const size_t SZ_H0 = (size_t)SLOW * BATCH * NO0 * NI0;  // 8,388,608
    const size_t SZ_H1 = (size_t)SLOW * BATCH * NO1 * NI1;  // 2,097,152
    float* h0   = w;
    float* c0   = h0 + SZ_H0;
    float* h1   = c0 + SZ_H0;
    float* c1   = h1 + SZ_H1;
    float* xf1T = c1 + SZ_H1;                                 // 8*128*128
    float* bm_g = xf1T + (size_t)BATCH * 128 * NO0;           // 8*64*16*128
    float* nb1  = bm_g + (size_t)BATCH * NO1 * MSG * NI1;     // 8*128*16
    float* nf_part = nb1 + (size_t)BATCH * NI1 * MSG;         // 8*128*4*16
    float* outsum_part = nf_part + (size_t)BATCH * NO0 * 4 * MSG;  // 8*64*2
    float* gradP  = outsum_part + BATCH * NO1 * 2;            // 512
    float* ohP    = gradP + BATCH * NO1;                      // 512
    float* WhT    = ohP + BATCH * NO1;                        // 128*32
    float* WfT    = WhT + 128 * SLOW;                         // 16*32
    float* WbT    = WfT + MSG * SLOW;                         // 16*32
    size_t total_floats = (size_t)(WbT - w) + MSG * SLOW;

    hipMemsetAsync(d_ws, 0, total_floats * sizeof(float), stream);
    k_prep<<<16, 256, 0, stream>>>(Wh, Wf, Wb, WhT, WfT, WbT);

    for (int t = 0; t < TSTEPS; t++) {
        if (t) k_merge<<<2560, 256, 0, stream>>>(h0, c0, h1, c1);
        k_l0<<<BATCH * NO0 * 4, 256, 0, stream>>>(inp, Wi, WhT, b_lstm, WfT, bf, ln_fs, ln_fb,
                                                  h0, c0, nb1, nf_part, t);
        k_xf<<<BATCH * 128, 128, 0, stream>>>(nf_part, Wi, xf1T);
        k_l1<<<BATCH * NO1 * 2, 256, 0, stream>>>(Wi, WhT, b_lstm, WfT, bf, ln_fs, ln_fb,
                                                  WbT, bwb, ln_bs, ln_bb,
                                                  h1, c1, xf1T, gradP, ohP, bm_g, outsum_part);
        k_red1<<<64, 256, 0, stream>>>(bm_g, nb1);
        k_out<<<BATCH, NO1, 0, stream>>>(outsum_part, labels, out, gradP, ohP, t);
    }
}

// Round 5
// 750.150 us; speedup vs baseline: 23.8020x; 1.9498x over previous
//
#include <hip/hip_runtime.h>
#include <hip/hip_bf16.h>

#define SLOW 32
#define MSG 16
#define TSTEPS 4
#define BATCH 8
#define NI0 256
#define NO0 128
#define NI1 128
#define NO1 64

__device__ __forceinline__ float rcpf(float x) { return __builtin_amdgcn_rcpf(x); }
__device__ __forceinline__ float sigf(float x) { return rcpf(1.f + __expf(-x)); }
__device__ __forceinline__ float tanh_apx(float x) {
    float xc = fminf(fmaxf(x, -15.f), 15.f);
    float e = __expf(-2.f * xc);
    return (1.f - e) * rcpf(1.f + e);
}

// ---------------------------------------------------------------------------
// prep: transpose Wh (32x128) -> WhT (128x32), Wf/Wb (32x16) -> WfT/WbT (16x32)
// ---------------------------------------------------------------------------
__global__ void k_prep(const float* __restrict__ Wh, const float* __restrict__ Wf,
                       const float* __restrict__ Wb,
                       float* __restrict__ WhT, float* __restrict__ WfT,
                       float* __restrict__ WbT) {
    int i = blockIdx.x * 256 + threadIdx.x;
    if (i < 128 * SLOW) {
        int j = i >> 7, k = i & 127;
        WhT[k * SLOW + j] = Wh[i];
    }
    if (i < MSG * SLOW) {
        int j = i >> 4, m = i & 15;
        WfT[m * SLOW + j] = Wf[i];
        WbT[m * SLOW + j] = Wb[i];
    }
}

// ---------------------------------------------------------------------------
// merge: for slow channels s<16, replace h/c with mean over batch (in place)
// ---------------------------------------------------------------------------
__global__ void k_merge(float* __restrict__ h0, float* __restrict__ c0,
                        float* __restrict__ h1, float* __restrict__ c1) {
    int idx = blockIdx.x * blockDim.x + threadIdx.x;
    const int P0 = NO0 * NI0;
    const int P1 = NO1 * NI1;
    const int N0 = 16 * P0;
    const int N1 = 16 * P1;
    float* h; float* c; int s, p, plane;
    if (idx < N0) { h = h0; c = c0; s = idx / P0; p = idx % P0; plane = P0; }
    else {
        idx -= N0;
        if (idx >= N1) return;
        h = h1; c = c1; s = idx / P1; p = idx % P1; plane = P1;
    }
    size_t base = (size_t)(s * BATCH) * plane + p;
    float sh = 0.f, sc = 0.f;
#pragma unroll
    for (int b = 0; b < BATCH; b++) { sh += h[base + (size_t)b * plane]; sc += c[base + (size_t)b * plane]; }
    sh *= 0.125f; sc *= 0.125f;
#pragma unroll
    for (int b = 0; b < BATCH; b++) { h[base + (size_t)b * plane] = sh; c[base + (size_t)b * plane] = sc; }
}

// ---------------------------------------------------------------------------
// Layer 0: block = (b,no,quarter), 256 threads = 4 s-groups x 64 cells.
// Weights staged in LDS (broadcast ds_read_b128, conflict-free).
// ---------------------------------------------------------------------------
__global__ __launch_bounds__(256) void k_l0(
    const float* __restrict__ inp, const float* __restrict__ Wi,
    const float* __restrict__ WhT, const float* __restrict__ b_lstm,
    const float* __restrict__ WfT, const float* __restrict__ bf,
    const float* __restrict__ ln_fs, const float* __restrict__ ln_fb,
    float* __restrict__ h0g, float* __restrict__ c0g,
    const float* __restrict__ nb1, float* __restrict__ nf_part, int t) {
    int q = blockIdx.x & 3;
    int no = (blockIdx.x >> 2) & 127;
    int b = blockIdx.x >> 9;
    int tid = threadIdx.x;
    int cl = tid & 63;                                   // local cell
    int sgu = __builtin_amdgcn_readfirstlane(tid >> 6);  // wave-uniform s-group
    int cell = q * 64 + cl;

    __shared__ __align__(16) float WhL[128 * SLOW];      // 16 KB
    __shared__ __align__(16) float WfL[MSG * SLOW];      // 2 KB
    __shared__ float h_lds[64 * 33];
    __shared__ float fm_lds[64 * 17];
    __shared__ float gsh[128];
    __shared__ float red[4][MSG];

    // stage weights (coalesced global read, linear LDS write)
#pragma unroll
    for (int i = tid; i < 128 * SLOW / 4; i += 256)
        ((float4*)WhL)[i] = ((const float4*)WhT)[i];
    if (tid < MSG * SLOW / 4)
        ((float4*)WfL)[tid] = ((const float4*)WfT)[tid];

    if (tid < 128) {
        int k = tid;
        float acc = b_lstm[k];
        const float* nbr = nb1 + ((size_t)b * NO0 + no) * MSG;
#pragma unroll
        for (int m = 0; m < MSG; m++) acc += nbr[m] * Wi[(MSG + m) * 128 + k];
        gsh[k] = acc;
    }

    float mi = inp[((size_t)t * BATCH + b) * NI0 + cell];
    const size_t SS = (size_t)BATCH * NO0 * NI0;
    size_t base = ((size_t)b * NO0 + no) * NI0 + cell;

    float c[8], hcur[8];
#pragma unroll
    for (int k = 0; k < 8; k++) {
        int s = sgu + 4 * k;
        hcur[k] = h0g[(size_t)s * SS + base];
        c[k] = c0g[(size_t)s * SS + base];
        h_lds[cl * 33 + s] = hcur[k];
    }
    __syncthreads();

    float hall[SLOW];
#pragma unroll
    for (int micro = 0; micro < 2; micro++) {
#pragma unroll
        for (int j = 0; j < SLOW; j++) hall[j] = h_lds[cl * 33 + j];
        __syncthreads();
#pragma unroll
        for (int k = 0; k < 8; k++) {
            int s = sgu + 4 * k;
            float a0 = gsh[s] + mi * Wi[s];
            float a1 = gsh[SLOW + s] + mi * Wi[SLOW + s];
            float a2 = gsh[2 * SLOW + s] + mi * Wi[2 * SLOW + s];
            float a3 = gsh[3 * SLOW + s] + mi * Wi[3 * SLOW + s];
#pragma unroll
            for (int j = 0; j < SLOW; j += 4) {
                float4 w0 = *(const float4*)&WhL[(s) * SLOW + j];
                float4 w1 = *(const float4*)&WhL[(SLOW + s) * SLOW + j];
                float4 w2 = *(const float4*)&WhL[(2 * SLOW + s) * SLOW + j];
                float4 w3 = *(const float4*)&WhL[(3 * SLOW + s) * SLOW + j];
                float x0 = hall[j], x1 = hall[j + 1], x2 = hall[j + 2], x3 = hall[j + 3];
                a0 += x0 * w0.x + x1 * w0.y + x2 * w0.z + x3 * w0.w;
                a1 += x0 * w1.x + x1 * w1.y + x2 * w1.z + x3 * w1.w;
                a2 += x0 * w2.x + x1 * w2.y + x2 * w2.z + x3 * w2.w;
                a3 += x0 * w3.x + x1 * w3.y + x2 * w3.z + x3 * w3.w;
            }
            float cn = sigf(a1) * c[k] + sigf(a0) * tanh_apx(a2);
            c[k] = cn;
            float hv = sigf(a3) * tanh_apx(cn);
            hcur[k] = hv;
            h_lds[cl * 33 + s] = hv;
        }
        __syncthreads();
    }

#pragma unroll
    for (int j = 0; j < SLOW; j++) hall[j] = h_lds[cl * 33 + j];

    // fm partial: this thread computes m = sgu*4 + mm
#pragma unroll
    for (int mm = 0; mm < 4; mm++) {
        int m = sgu * 4 + mm;
        float a = bf[m];
#pragma unroll
        for (int j = 0; j < SLOW; j += 4) {
            float4 w = *(const float4*)&WfL[m * SLOW + j];
            a += hall[j] * w.x + hall[j + 1] * w.y + hall[j + 2] * w.z + hall[j + 3] * w.w;
        }
        fm_lds[cl * 17 + m] = a;
    }

    // state writeback (overlaps with fm exchange)
#pragma unroll
    for (int k = 0; k < 8; k++) {
        int s = sgu + 4 * k;
        h0g[(size_t)s * SS + base] = hcur[k];
        c0g[(size_t)s * SS + base] = c[k];
    }
    __syncthreads();

    float fm[MSG];
#pragma unroll
    for (int m = 0; m < MSG; m++) fm[m] = fm_lds[cl * 17 + m];
    float mean = 0.f;
#pragma unroll
    for (int m = 0; m < MSG; m++) mean += fm[m];
    mean *= (1.f / MSG);
    float var = 0.f;
#pragma unroll
    for (int m = 0; m < MSG; m++) { float d = fm[m] - mean; var += d * d; }
    var *= (1.f / MSG);
    float rs = rsqrtf(var + 1e-6f);
#pragma unroll
    for (int m = 0; m < MSG; m++) fm[m] = (fm[m] - mean) * rs * ln_fs[m] + ln_fb[m];

    // raw partial sum over the block's 256 threads (each cell counted 4x)
    int lane = tid & 63, wv = tid >> 6;
#pragma unroll
    for (int m = 0; m < MSG; m++) {
        float v = fm[m];
#pragma unroll
        for (int d = 1; d < 64; d <<= 1) v += __shfl_xor(v, d);
        if (lane == 0) red[wv][m] = v;
    }
    __syncthreads();
    if (tid < MSG) {
        float a = red[0][tid] + red[1][tid] + red[2][tid] + red[3][tid];
        nf_part[(((size_t)b * NO0 + no) * 4 + q) * MSG + tid] = a;
    }
}

// ---------------------------------------------------------------------------
// k_xf: xf1T[b][k][no0] = sum_m nf[b,no0,m] * Wi[m,k], nf = sum_q part / 1024
// ---------------------------------------------------------------------------
__global__ __launch_bounds__(128) void k_xf(const float* __restrict__ nf_part,
                                            const float* __restrict__ Wi,
                                            float* __restrict__ xf1T) {
    int b = blockIdx.x >> 7;
    int k = blockIdx.x & 127;
    int no = threadIdx.x;
    float nf[MSG];
#pragma unroll
    for (int m = 0; m < MSG; m++) nf[m] = 0.f;
    const float* p = nf_part + ((size_t)b * NO0 + no) * 4 * MSG;
#pragma unroll
    for (int qm = 0; qm < 4 * MSG; qm++) nf[qm & 15] += p[qm];
    float a = 0.f;
#pragma unroll
    for (int m = 0; m < MSG; m++) a += nf[m] * Wi[m * 128 + k];
    xf1T[((size_t)b * 128 + k) * NO0 + no] = a * (1.f / 1024.f);
}

// ---------------------------------------------------------------------------
// Layer 1: block = (b,no,half), 256 threads = 4 s-groups x 64 cells.
// ---------------------------------------------------------------------------
__global__ __launch_bounds__(256) void k_l1(
    const float* __restrict__ Wi, const float* __restrict__ WhT,
    const float* __restrict__ b_lstm,
    const float* __restrict__ WfT, const float* __restrict__ bf,
    const float* __restrict__ ln_fs, const float* __restrict__ ln_fb,
    const float* __restrict__ WbT, const float* __restrict__ bwb,
    const float* __restrict__ ln_bs, const float* __restrict__ ln_bb,
    float* __restrict__ h1g, float* __restrict__ c1g,
    const float* __restrict__ xf1T, const float* __restrict__ gradP,
    const float* __restrict__ ohP,
    float* __restrict__ bm_g, float* __restrict__ outsum_part) {
    int q = blockIdx.x & 1;
    int no = (blockIdx.x >> 1) & 63;
    int b = blockIdx.x >> 7;
    int tid = threadIdx.x;
    int cl = tid & 63;
    int sgu = __builtin_amdgcn_readfirstlane(tid >> 6);
    int cell = q * 64 + cl;

    __shared__ __align__(16) float WhL[128 * SLOW];
    __shared__ __align__(16) float WfL[MSG * SLOW];
    __shared__ __align__(16) float WbL[MSG * SLOW];
    __shared__ float h_lds[64 * 33];
    __shared__ float msg_lds[64 * 17];
    __shared__ float gsh[128];
    __shared__ float red[4];

#pragma unroll
    for (int i = tid; i < 128 * SLOW / 4; i += 256)
        ((float4*)WhL)[i] = ((const float4*)WhT)[i];
    if (tid < MSG * SLOW / 4) {
        ((float4*)WfL)[tid] = ((const float4*)WfT)[tid];
        ((float4*)WbL)[tid] = ((const float4*)WbT)[tid];
    }

    if (tid < 128) {
        int k = tid;
        float g = gradP[b * NO1 + no], oh = ohP[b * NO1 + no];
        gsh[k] = b_lstm[k] + g * Wi[MSG * 128 + k] + oh * Wi[(MSG + 1) * 128 + k];
    }

    const float* xfb = xf1T + (size_t)b * 128 * NI1;  // [gate][ni]
    const size_t SS = (size_t)BATCH * NO1 * NI1;
    size_t base = ((size_t)b * NO1 + no) * NI1 + cell;

    float xf0[8], xf1[8], xf2[8], xf3[8];
#pragma unroll
    for (int k = 0; k < 8; k++) {
        int s = sgu + 4 * k;
        xf0[k] = xfb[s * NI1 + cell];
        xf1[k] = xfb[(SLOW + s) * NI1 + cell];
        xf2[k] = xfb[(2 * SLOW + s) * NI1 + cell];
        xf3[k] = xfb[(3 * SLOW + s) * NI1 + cell];
    }

    float c[8], hcur[8];
#pragma unroll
    for (int k = 0; k < 8; k++) {
        int s = sgu + 4 * k;
        hcur[k] = h1g[(size_t)s * SS + base];
        c[k] = c1g[(size_t)s * SS + base];
        h_lds[cl * 33 + s] = hcur[k];
    }
    __syncthreads();

    float hall[SLOW];
#pragma unroll
    for (int micro = 0; micro < 2; micro++) {
#pragma unroll
        for (int j = 0; j < SLOW; j++) hall[j] = h_lds[cl * 33 + j];
        __syncthreads();
#pragma unroll
        for (int k = 0; k < 8; k++) {
            int s = sgu + 4 * k;
            float a0 = gsh[s] + xf0[k];
            float a1 = gsh[SLOW + s] + xf1[k];
            float a2 = gsh[2 * SLOW + s] + xf2[k];
            float a3 = gsh[3 * SLOW + s] + xf3[k];
#pragma unroll
            for (int j = 0; j < SLOW; j += 4) {
                float4 w0 = *(const float4*)&WhL[(s) * SLOW + j];
                float4 w1 = *(const float4*)&WhL[(SLOW + s) * SLOW + j];
                float4 w2 = *(const float4*)&WhL[(2 * SLOW + s) * SLOW + j];
                float4 w3 = *(const float4*)&WhL[(3 * SLOW + s) * SLOW + j];
                float x0 = hall[j], x1 = hall[j + 1], x2 = hall[j + 2], x3 = hall[j + 3];
                a0 += x0 * w0.x + x1 * w0.y + x2 * w0.z + x3 * w0.w;
                a1 += x0 * w1.x + x1 * w1.y + x2 * w1.z + x3 * w1.w;
                a2 += x0 * w2.x + x1 * w2.y + x2 * w2.z + x3 * w2.w;
                a3 += x0 * w3.x + x1 * w3.y + x2 * w3.z + x3 * w3.w;
            }
            float cn = sigf(a1) * c[k] + sigf(a0) * tanh_apx(a2);
            c[k] = cn;
            float hv = sigf(a3) * tanh_apx(cn);
            hcur[k] = hv;
            h_lds[cl * 33 + s] = hv;
        }
        __syncthreads();
    }

#pragma unroll
    for (int j = 0; j < SLOW; j++) hall[j] = h_lds[cl * 33 + j];

    // ---- fm (need LN'd channel 0) ----
#pragma unroll
    for (int mm = 0; mm < 4; mm++) {
        int m = sgu * 4 + mm;
        float a = bf[m];
#pragma unroll
        for (int j = 0; j < SLOW; j += 4) {
            float4 w = *(const float4*)&WfL[m * SLOW + j];
            a += hall[j] * w.x + hall[j + 1] * w.y + hall[j + 2] * w.z + hall[j + 3] * w.w;
        }
        msg_lds[cl * 17 + m] = a;
    }

    // state writeback
#pragma unroll
    for (int k = 0; k < 8; k++) {
        int s = sgu + 4 * k;
        h1g[(size_t)s * SS + base] = hcur[k];
        c1g[(size_t)s * SS + base] = c[k];
    }
    __syncthreads();

    float fm0;
    {
        float fmv[MSG];
#pragma unroll
        for (int m = 0; m < MSG; m++) fmv[m] = msg_lds[cl * 17 + m];
        float mean = 0.f;
#pragma unroll
        for (int m = 0; m < MSG; m++) mean += fmv[m];
        mean *= (1.f / MSG);
        float var = 0.f;
#pragma unroll
        for (int m = 0; m < MSG; m++) { float d = fmv[m] - mean; var += d * d; }
        var *= (1.f / MSG);
        float rs = rsqrtf(var + 1e-6f);
        fm0 = (fmv[0] - mean) * rs * ln_fs[0] + ln_fb[0];
    }
    __syncthreads();  // msg_lds reads done before bm overwrites

    // ---- bm ----
#pragma unroll
    for (int mm = 0; mm < 4; mm++) {
        int m = sgu * 4 + mm;
        float a = bwb[m];
#pragma unroll
        for (int j = 0; j < SLOW; j += 4) {
            float4 w = *(const float4*)&WbL[m * SLOW + j];
            a += hall[j] * w.x + hall[j + 1] * w.y + hall[j + 2] * w.z + hall[j + 3] * w.w;
        }
        msg_lds[cl * 17 + m] = a;
    }
    __syncthreads();
    {
        float bmv[MSG];
#pragma unroll
        for (int m = 0; m < MSG; m++) bmv[m] = msg_lds[cl * 17 + m];
        float mean = 0.f;
#pragma unroll
        for (int m = 0; m < MSG; m++) mean += bmv[m];
        mean *= (1.f / MSG);
        float var = 0.f;
#pragma unroll
        for (int m = 0; m < MSG; m++) { float d = bmv[m] - mean; var += d * d; }
        var *= (1.f / MSG);
        float rs = rsqrtf(var + 1e-6f);
#pragma unroll
        for (int m = 0; m < MSG; m++) bmv[m] = (bmv[m] - mean) * rs * ln_bs[m] + ln_bb[m];
#pragma unroll
        for (int mm = 0; mm < 4; mm++) {
            int m = sgu * 4 + mm;
            bm_g[(((size_t)b * NO1 + no) * MSG + m) * NI1 + cell] = bmv[m];
        }
    }

    // raw partial sum of fm0 over block (each cell counted 4x)
    int lane = tid & 63, wv = tid >> 6;
    float v = fm0;
#pragma unroll
    for (int d = 1; d < 64; d <<= 1) v += __shfl_xor(v, d);
    if (lane == 0) red[wv] = v;
    __syncthreads();
    if (tid == 0)
        outsum_part[((size_t)b * NO1 + no) * 2 + q] = red[0] + red[1] + red[2] + red[3];
}

// ---------------------------------------------------------------------------
// nb1[b,ni,m] = mean over no of bm_g
// ---------------------------------------------------------------------------
__global__ void k_red1(const float* __restrict__ bm_g, float* __restrict__ nb1) {
    int g = blockIdx.x * 256 + threadIdx.x;  // < 8*128*16 = 16384
    int ni = g & 127;
    int m = (g >> 7) & 15;
    int b = g >> 11;
    float a = 0.f;
#pragma unroll 8
    for (int no = 0; no < NO1; no++)
        a += bm_g[(((size_t)b * NO1 + no) * MSG + m) * NI1 + ni];
    nb1[((size_t)b * NI1 + ni) * MSG + m] = a * (1.f / NO1);
}

// ---------------------------------------------------------------------------
// out/softmax/error: block per b (64 threads = classes)
// ---------------------------------------------------------------------------
__global__ void k_out(const float* __restrict__ outsum_part, const int* __restrict__ labels,
                      float* __restrict__ dout, float* __restrict__ gradP,
                      float* __restrict__ ohP, int t) {
    int b = blockIdx.x;
    int no = threadIdx.x;
    float v = (outsum_part[((size_t)b * NO1 + no) * 2] +
               outsum_part[((size_t)b * NO1 + no) * 2 + 1]) * (1.f / 512.f);
    float mx = v;
#pragma unroll
    for (int d = 1; d < 64; d <<= 1) mx = fmaxf(mx, __shfl_xor(mx, d));
    float e = __expf(v - mx);
    float sum = e;
#pragma unroll
    for (int d = 1; d < 64; d <<= 1) sum += __shfl_xor(sum, d);
    int lbl = labels[t * BATCH + b];
    float oh = (no == lbl) ? 1.f : 0.f;
    gradP[b * NO1 + no] = e / sum - oh;
    ohP[b * NO1 + no] = oh;
    dout[((size_t)t * BATCH + b) * NO1 + no] = v;
}

// ---------------------------------------------------------------------------

extern "C" void kernel_launch(void* const* d_in, const int* in_sizes, int n_in,
                              void* d_out, int out_size, void* d_ws, size_t ws_size,
                              hipStream_t stream) {
    const float* inp   = (const float*)d_in[0];
    const int*   labels= (const int*)d_in[1];
    const float* Wi    = (const float*)d_in[2];
    const float* Wh    = (const float*)d_in[3];
    const float* b_lstm= (const float*)d_in[4];
    const float* Wf    = (const float*)d_in[5];
    const float* bf    = (const float*)d_in[6];
    const float* Wb    = (const float*)d_in[7];
    const float* bwb   = (const float*)d_in[8];
    const float* ln_fs = (const float*)d_in[9];
    const float* ln_fb = (const float*)d_in[10];
    const float* ln_bs = (const float*)d_in[11];
    const float* ln_bb = (const float*)d_in[12];
    float* out = (float*)d_out;

    float* w = (float*)d_ws;
    const size_t SZ_H0 = (size_t)SLOW * BATCH * NO0 * NI0;  // 8,388,608
    const size_t SZ_H1 = (size_t)SLOW * BATCH * NO1 * NI1;  // 2,097,152
    float* h0   = w;
    float* c0   = h0 + SZ_H0;
    float* h1   = c0 + SZ_H0;
    float* c1   = h1 + SZ_H1;
    float* xf1T = c1 + SZ_H1;                                 // 8*128*128
    float* bm_g = xf1T + (size_t)BATCH * 128 * NO0;           // 8*64*16*128
    float* nb1  = bm_g + (size_t)BATCH * NO1 * MSG * NI1;     // 8*128*16
    float* nf_part = nb1 + (size_t)BATCH * NI1 * MSG;         // 8*128*4*16
    float* outsum_part = nf_part + (size_t)BATCH * NO0 * 4 * MSG;  // 8*64*2
    float* gradP  = outsum_part + BATCH * NO1 * 2;            // 512
    float* ohP    = gradP + BATCH * NO1;                      // 512
    float* WhT    = ohP + BATCH * NO1;                        // 128*32
    float* WfT    = WhT + 128 * SLOW;                         // 16*32
    float* WbT    = WfT + MSG * SLOW;                         // 16*32
    size_t total_floats = (size_t)(WbT - w) + MSG * SLOW;

    hipMemsetAsync(d_ws, 0, total_floats * sizeof(float), stream);
    k_prep<<<16, 256, 0, stream>>>(Wh, Wf, Wb, WhT, WfT, WbT);

    for (int t = 0; t < TSTEPS; t++) {
        if (t) k_merge<<<2560, 256, 0, stream>>>(h0, c0, h1, c1);
        k_l0<<<BATCH * NO0 * 4, 256, 0, stream>>>(inp, Wi, WhT, b_lstm, WfT, bf, ln_fs, ln_fb,
                                                  h0, c0, nb1, nf_part, t);
        k_xf<<<BATCH * 128, 128, 0, stream>>>(nf_part, Wi, xf1T);
        k_l1<<<BATCH * NO1 * 2, 256, 0, stream>>>(Wi, WhT, b_lstm, WfT, bf, ln_fs, ln_fb,
                                                  WbT, bwb, ln_bs, ln_bb,
                                                  h1, c1, xf1T, gradP, ohP, bm_g, outsum_part);
        k_red1<<<64, 256, 0, stream>>>(bm_g, nb1);
        k_out<<<BATCH, NO1, 0, stream>>>(outsum_part, labels, out, gradP, ohP, t);
    }
}